// Round 2
// baseline (203.820 us; speedup 1.0000x reference)
//
#include <hip/hip_runtime.h>

#define DM    128
#define DI    256
#define NH    8
#define HD    32
#define NS    64
#define CDIM  384
#define DPROJ 648
#define LSEQ  4096
#define NB    8
#define NTOK  32768          // NB*LSEQ
#define LC    64             // chunk length
#define NC    64             // chunks per (b,h) sequence
#define EPSF  1e-5f
#define LOG2E 1.4426950408889634f

typedef __bf16 bf16;
typedef bf16  bf16x8 __attribute__((ext_vector_type(8)));
typedef bf16  bf16x4 __attribute__((ext_vector_type(4)));
typedef short short8 __attribute__((ext_vector_type(8)));
typedef float f32x4  __attribute__((ext_vector_type(4)));

__device__ __forceinline__ unsigned short f2bfbits(float f) {
    unsigned int u = __float_as_uint(f);
    unsigned int r = u + 0x7FFFu + ((u >> 16) & 1u);   // RNE
    return (unsigned short)(r >> 16);
}
__device__ __forceinline__ float bfbits2f(unsigned short u) {
    return __uint_as_float(((unsigned int)u) << 16);
}

// ---------------- 0. prep: w1 cast + w2 fragment-pack (gnorm folded) -----------
// w2f layout: frag f = kk*8+nt (kk = k/32, nt = n/16), lane l = ko*16+fr,
//   w2f[f*512 + l*8 + j] = bf16( W2[nt*16+fr][kk*32+ko*8+j] * gw[k] )
// -> in gemm2 each wave's B-fragment is ONE coalesced 1KB load.
__global__ __launch_bounds__(256) void k_prep(const float* __restrict__ a,
                                              const float* __restrict__ b,
                                              const float* __restrict__ gw,
                                              unsigned short* __restrict__ oa,
                                              unsigned short* __restrict__ ow,
                                              int na) {
    int i = blockIdx.x * 256 + threadIdx.x;
    if (i < na) oa[i] = f2bfbits(a[i]);
    else {
        int j = i - na;
        if (j < DM * DI) {
            int f = j >> 9, r = j & 511;
            int lane = r >> 3, jj = r & 7;
            int kk = f >> 3, nt = f & 7;
            int fr = lane & 15, ko = lane >> 4;
            int n = nt * 16 + fr, k = kk * 32 + ko * 8 + jj;
            ow[j] = f2bfbits(b[n * DI + k] * gw[k]);
        }
    }
}

// ---------------- 1. fused input RMSNorm + dt ----------------------------------
__global__ __launch_bounds__(256) void k_rmsdt(const float* __restrict__ x,
                                               const float* __restrict__ w,
                                               const float* __restrict__ w1,
                                               const float* __restrict__ dtb,
                                               unsigned short* __restrict__ xnb,
                                               float* __restrict__ dtf) {
    __shared__ float Xs[4][132];
    __shared__ float Wd[8][132];
    const int t = threadIdx.x;
    {
        int row = t >> 5, col = (t & 31) * 4;           // 8x128 = 256 float4
        *(float4*)&Wd[row][col] = *(const float4*)(w1 + (size_t)(640 + row) * DM + col);
    }
    const int wave = t >> 6, lane = t & 63;
    const size_t row = (size_t)blockIdx.x * 4 + wave;
    const float* xr = x + row * DM + lane * 2;
    float v0 = xr[0], v1 = xr[1];
    float ss = v0 * v0 + v1 * v1;
    #pragma unroll
    for (int o = 32; o; o >>= 1) ss += __shfl_xor(ss, o);
    float r = rsqrtf(ss * (1.0f / DM) + EPSF);
    float o0 = v0 * r * w[lane * 2], o1 = v1 * r * w[lane * 2 + 1];
    Xs[wave][lane * 2] = o0; Xs[wave][lane * 2 + 1] = o1;
    ushort2 ob; ob.x = f2bfbits(o0); ob.y = f2bfbits(o1);
    *(ushort2*)(xnb + row * DM + lane * 2) = ob;
    __syncthreads();
    const int h = lane >> 3, ks = lane & 7;
    float acc = 0.f;
    #pragma unroll
    for (int i = 0; i < 4; i++) {
        float4 xv = *(const float4*)&Xs[wave][ks * 16 + i * 4];
        float4 wv = *(const float4*)&Wd[h][ks * 16 + i * 4];
        acc = fmaf(xv.x, wv.x, acc);
        acc = fmaf(xv.y, wv.y, acc);
        acc = fmaf(xv.z, wv.z, acc);
        acc = fmaf(xv.w, wv.w, acc);
    }
    acc += __shfl_xor(acc, 1);
    acc += __shfl_xor(acc, 2);
    acc += __shfl_xor(acc, 4);
    if (ks == 0) {
        float v = acc + dtb[h];
        dtf[row * NH + h] = (v > 20.f) ? v : log1pf(expf(v));
    }
}

// ---------------- 2. GEMM1 (bf16 MFMA): split bf16 out (z | xBC), N=640 --------
__global__ __launch_bounds__(256) void k_gemm1(const unsigned short* __restrict__ A,
                                               const unsigned short* __restrict__ B,
                                               unsigned short* __restrict__ zb,
                                               unsigned short* __restrict__ xbc) {
    __shared__ bf16 As[64 * 40];
    __shared__ bf16 Bs[64 * 40];
    const int t = threadIdx.x;
    const int m0 = blockIdx.x * 64, n0 = blockIdx.y * 64;
    const int wave = t >> 6, lane = t & 63;
    const int wm = wave >> 1, wn = wave & 1;
    const int fr = lane & 15, fk = (lane >> 4) * 8;
    f32x4 acc[2][2] = {};
    const int r = t >> 2, q = (t & 3) * 8;
    for (int k0 = 0; k0 < DM; k0 += 32) {
        __syncthreads();
        *(short8*)&As[r * 40 + q] = *(const short8*)(A + (size_t)(m0 + r) * DM + k0 + q);
        *(short8*)&Bs[r * 40 + q] = *(const short8*)(B + (size_t)(n0 + r) * DM + k0 + q);
        __syncthreads();
        #pragma unroll
        for (int mt = 0; mt < 2; mt++) {
            bf16x8 af = *(const bf16x8*)&As[(wm * 32 + mt * 16 + fr) * 40 + fk];
            #pragma unroll
            for (int nt = 0; nt < 2; nt++) {
                bf16x8 bf = *(const bf16x8*)&Bs[(wn * 32 + nt * 16 + fr) * 40 + fk];
                acc[mt][nt] = __builtin_amdgcn_mfma_f32_16x16x32_bf16(af, bf, acc[mt][nt], 0, 0, 0);
            }
        }
    }
    #pragma unroll
    for (int mt = 0; mt < 2; mt++)
        #pragma unroll
        for (int nt = 0; nt < 2; nt++) {
            int n = n0 + wn * 32 + nt * 16 + fr;        // < 640 always (grid.y=10)
            #pragma unroll
            for (int rr = 0; rr < 4; rr++) {
                int m = m0 + wm * 32 + mt * 16 + (lane >> 4) * 4 + rr;
                unsigned short v = f2bfbits(acc[mt][nt][rr]);
                if (n < DI) zb[(size_t)m * DI + n] = v;
                else        xbc[(size_t)m * CDIM + (n - 256)] = v;
            }
        }
}

// ---------------- 3. causal dw-conv (K=4) + SiLU; triple-layout output ---------
__global__ __launch_bounds__(384) void k_conv(const unsigned short* __restrict__ xbc,
                                              const float* __restrict__ cw,
                                              const float* __restrict__ cb,
                                              unsigned short* __restrict__ bcA,
                                              unsigned short* __restrict__ xT,
                                              unsigned short* __restrict__ bT) {
    __shared__ __align__(16) unsigned short L[320][72];
    const int c = threadIdx.x;
    const int t0 = blockIdx.x * 64;
    const int l0 = t0 & (LSEQ - 1);
    float4 wv = *(const float4*)(cw + c * 4);
    float bias = cb[c];
    const unsigned short* in = xbc + (size_t)t0 * CDIM + c;
    float h1 = 0.f, h2 = 0.f, h3 = 0.f;
    if (l0) {
        h1 = bfbits2f(in[-CDIM]);
        h2 = bfbits2f(in[-2 * CDIM]);
        h3 = bfbits2f(in[-3 * CDIM]);
    }
    short8 pk;
    #pragma unroll 8
    for (int t = 0; t < 64; t++) {
        float x0 = bfbits2f(in[(size_t)t * CDIM]);
        float acc = bias;
        acc = fmaf(x0, wv.w, acc);
        acc = fmaf(h1, wv.z, acc);
        acc = fmaf(h2, wv.y, acc);
        acc = fmaf(h3, wv.x, acc);
        float s = acc / (1.f + expf(-acc));
        unsigned short us = f2bfbits(s);
        if (c >= 256) bcA[(size_t)(t0 + t) * 128 + (c - 256)] = us;   // B|C token-major
        pk[t & 7] = (short)us;
        if (c < 320 && (t & 7) == 7) *(short8*)&L[c][t - 7] = pk;
        h3 = h2; h2 = h1; h1 = x0;
    }
    __syncthreads();
    #pragma unroll
    for (int it = 0; it < 7; it++) {
        int idx = it * 384 + c;
        if (idx < 2560) {                       // 320 rows x 8 token-chunks
            int row = idx >> 3, tc = (idx & 7) * 8;
            short8 v = *(const short8*)&L[row][tc];
            unsigned short* dst = (row < 256)
                ? xT + (size_t)row * NTOK + t0 + tc
                : bT + (size_t)(row - 256) * NTOK + t0 + tc;
            *(short8*)dst = v;
        }
    }
}

// ---------------- 5a. SSD pass 1: chunk-local end state, all-global frags ------
__global__ __launch_bounds__(256, 4) void k_ssd1(const unsigned short* __restrict__ bT,
                                                 const unsigned short* __restrict__ xT,
                                                 const float* __restrict__ dtf,
                                                 const float* __restrict__ alog,
                                                 unsigned short* __restrict__ hst,
                                                 float* __restrict__ dAp) {
    __shared__ __align__(16) float wl[4][64];
    const int bh = blockIdx.x >> 4, cg = blockIdx.x & 15;
    const int b = bh >> 3, h = bh & 7;
    const int wave = threadIdx.x >> 6, lane = threadIdx.x & 63;
    const int c = cg * 4 + wave;
    const size_t tok0 = (size_t)b * LSEQ + c * LC;
    const float A = -expf(alog[h]);
    float dt = dtf[(tok0 + lane) * NH + h];
    float q = dt * A * LOG2E;
    #pragma unroll
    for (int o = 1; o <= 32; o <<= 1) {
        float tmp = __shfl_up(q, o);
        if (lane >= o) q += tmp;
    }
    float qL = __shfl(q, 63);
    wl[wave][lane] = exp2f(qL - q) * dt;
    if (lane == 0) dAp[(size_t)bh * NC + c] = exp2f(qL);
    __syncthreads();
    const int m = lane & 15, ko = lane >> 4;
    f32x4 hacc[4][2] = {};
    #pragma unroll
    for (int kh = 0; kh < 2; kh++) {
        bf16x8 xb[2];
        #pragma unroll
        for (int pi = 0; pi < 2; pi++)
            xb[pi] = *(const bf16x8*)(xT + (size_t)(h * HD + pi * 16 + m) * NTOK + tok0 + kh * 32 + ko * 8);
        f32x4 w0 = *(const f32x4*)&wl[wave][kh * 32 + ko * 8];
        f32x4 w1 = *(const f32x4*)&wl[wave][kh * 32 + ko * 8 + 4];
        #pragma unroll
        for (int ni = 0; ni < 4; ni++) {
            bf16x8 bv = *(const bf16x8*)(bT + (size_t)(ni * 16 + m) * NTOK + tok0 + kh * 32 + ko * 8);
            bf16x8 af;
            #pragma unroll
            for (int j = 0; j < 4; j++) af[j] = (bf16)((float)bv[j] * w0[j]);
            #pragma unroll
            for (int j = 0; j < 4; j++) af[4 + j] = (bf16)((float)bv[4 + j] * w1[j]);
            #pragma unroll
            for (int pi = 0; pi < 2; pi++)
                hacc[ni][pi] = __builtin_amdgcn_mfma_f32_16x16x32_bf16(af, xb[pi], hacc[ni][pi], 0, 0, 0);
        }
    }
    unsigned short* hb = hst + (((size_t)bh * NC + c) << 11);
    #pragma unroll
    for (int ni = 0; ni < 4; ni++)
        #pragma unroll
        for (int pi = 0; pi < 2; pi++) {
            bf16x4 pv;
            #pragma unroll
            for (int r = 0; r < 4; r++) pv[r] = (bf16)hacc[ni][pi][r];
            *(bf16x4*)(hb + (pi * 16 + m) * 64 + ni * 16 + ko * 4) = pv;
        }
}

// ---------------- 5b. SSM pass 2: scan over bf16 chunk states ------------------
__global__ __launch_bounds__(256) void k_ssm2(unsigned short* __restrict__ hst,
                                              const float* __restrict__ dAp) {
    __shared__ float dl[2][NC];
    const int pr = blockIdx.x >> 3, seg = blockIdx.x & 7;
    const int bh0 = pr * 2, bh1 = pr * 2 + 1;
    const int s = seg * 256 + threadIdx.x;
    if (threadIdx.x < NC) dl[0][threadIdx.x] = dAp[(size_t)bh0 * NC + threadIdx.x];
    else if (threadIdx.x < 2 * NC) dl[1][threadIdx.x - NC] = dAp[(size_t)bh1 * NC + threadIdx.x - NC];
    __syncthreads();
    unsigned short* b0 = hst + ((size_t)bh0 * NC << 11) + s;
    unsigned short* b1 = hst + ((size_t)bh1 * NC << 11) + s;
    float r0 = 0.f, r1 = 0.f;
    float n0 = bfbits2f(b0[0]), n1 = bfbits2f(b1[0]);
    for (int c = 0; c < NC; c++) {
        float t0 = n0, t1 = n1;
        if (c + 1 < NC) {
            n0 = bfbits2f(b0[(size_t)(c + 1) << 11]);
            n1 = bfbits2f(b1[(size_t)(c + 1) << 11]);
        }
        b0[(size_t)c << 11] = f2bfbits(r0);
        b1[(size_t)c << 11] = f2bfbits(r1);
        r0 = fmaf(r0, dl[0][c], t0);
        r1 = fmaf(r1, dl[1][c], t1);
    }
}

// ---------------- 5c. SSD pass 3: Y = P.X + diag(2^q).(C.h_in^T) ---------------
__global__ __launch_bounds__(256, 2) void k_ssd3(const unsigned short* __restrict__ bcA,
                                                 const unsigned short* __restrict__ xT,
                                                 const float* __restrict__ dtf,
                                                 const float* __restrict__ alog,
                                                 const unsigned short* __restrict__ hst,
                                                 const float* __restrict__ Dw,
                                                 unsigned short* __restrict__ ybb) {
    __shared__ __align__(16) bf16 Pl[4][64 * 72];
    __shared__ __align__(16) float ql[4][64];
    __shared__ __align__(16) float dl[4][64];
    const int bh = blockIdx.x >> 4, cg = blockIdx.x & 15;
    const int b = bh >> 3, h = bh & 7;
    const int wave = threadIdx.x >> 6, lane = threadIdx.x & 63;
    const int c = cg * 4 + wave;
    const size_t tok0 = (size_t)b * LSEQ + c * LC;
    const float A = -expf(alog[h]);
    const float Dh = Dw[h];
    float dt = dtf[(tok0 + lane) * NH + h];
    float q = dt * A * LOG2E;
    #pragma unroll
    for (int o = 1; o <= 32; o <<= 1) {
        float tmp = __shfl_up(q, o);
        if (lane >= o) q += tmp;
    }
    ql[wave][lane] = q;
    dl[wave][lane] = dt;
    const int m = lane & 15, ko = lane >> 4;
    bf16x8 cf[4][2];
    #pragma unroll
    for (int ti = 0; ti < 4; ti++)
        #pragma unroll
        for (int kh = 0; kh < 2; kh++)
            cf[ti][kh] = *(const bf16x8*)(bcA + (tok0 + ti * 16 + m) * 128 + 64 + kh * 32 + ko * 8);
    f32x4 gt[4][4] = {};
    #pragma unroll
    for (int kh = 0; kh < 2; kh++) {
        bf16x8 bfg[4];
        #pragma unroll
        for (int si = 0; si < 4; si++)
            bfg[si] = *(const bf16x8*)(bcA + (tok0 + si * 16 + m) * 128 + kh * 32 + ko * 8);
        #pragma unroll
        for (int ti = 0; ti < 4; ti++)
            #pragma unroll
            for (int si = 0; si < 4; si++)
                gt[ti][si] = __builtin_amdgcn_mfma_f32_16x16x32_bf16(bfg[si], cf[ti][kh], gt[ti][si], 0, 0, 0);
    }
    __syncthreads();
    float qt[4];
    #pragma unroll
    for (int ti = 0; ti < 4; ti++) qt[ti] = ql[wave][ti * 16 + m];
    #pragma unroll
    for (int si = 0; si < 4; si++) {
        f32x4 qs = *(const f32x4*)&ql[wave][si * 16 + ko * 4];
        f32x4 ds = *(const f32x4*)&dl[wave][si * 16 + ko * 4];
        #pragma unroll
        for (int ti = 0; ti < 4; ti++) {
            bf16x4 pv = {};
            if (si <= ti) {
                const int t = ti * 16 + m;
                #pragma unroll
                for (int r = 0; r < 4; r++) {
                    int s = si * 16 + ko * 4 + r;
                    float p = 0.f;
                    if (s <= t) {
                        p = exp2f(qt[ti] - qs[r]) * ds[r] * gt[ti][si][r];
                        if (s == t) p += Dh;
                    }
                    pv[r] = (bf16)p;
                }
            }
            *(bf16x4*)&Pl[wave][(ti * 16 + m) * 72 + si * 16 + ko * 4] = pv;
        }
    }
    __syncthreads();
    f32x4 et[4];
    #pragma unroll
    for (int ti = 0; ti < 4; ti++) {
        f32x4 qv = *(const f32x4*)&ql[wave][ti * 16 + ko * 4];
        #pragma unroll
        for (int r = 0; r < 4; r++) et[ti][r] = exp2f(qv[r]);
    }
    const size_t hbase = ((size_t)bh * NC + c) << 11;
    f32x4 ya[4][2] = {}, ua[4][2] = {};
    #pragma unroll
    for (int kh = 0; kh < 2; kh++) {
        bf16x8 xb[2], hb2[2];
        #pragma unroll
        for (int pi = 0; pi < 2; pi++) {
            xb[pi]  = *(const bf16x8*)(xT + (size_t)(h * HD + pi * 16 + m) * NTOK + tok0 + kh * 32 + ko * 8);
            hb2[pi] = *(const bf16x8*)(hst + hbase + (pi * 16 + m) * 64 + kh * 32 + ko * 8);
        }
        #pragma unroll
        for (int ti = 0; ti < 4; ti++) {
            bf16x8 pa = *(const bf16x8*)&Pl[wave][(ti * 16 + m) * 72 + kh * 32 + ko * 8];
            #pragma unroll
            for (int pi = 0; pi < 2; pi++) {
                ya[ti][pi] = __builtin_amdgcn_mfma_f32_16x16x32_bf16(pa, xb[pi], ya[ti][pi], 0, 0, 0);
                ua[ti][pi] = __builtin_amdgcn_mfma_f32_16x16x32_bf16(cf[ti][kh], hb2[pi], ua[ti][pi], 0, 0, 0);
            }
        }
    }
    unsigned short* yrow = ybb + tok0 * DI + h * HD;
    #pragma unroll
    for (int ti = 0; ti < 4; ti++)
        #pragma unroll
        for (int pi = 0; pi < 2; pi++)
            #pragma unroll
            for (int r = 0; r < 4; r++) {
                int t = ti * 16 + ko * 4 + r;
                yrow[(size_t)t * DI + pi * 16 + m] =
                    f2bfbits(ya[ti][pi][r] + et[ti][r] * ua[ti][pi][r]);
            }
}

// ---------------- 6+7. fused gate + GEMM2 + residual (no LDS, frag-packed W2) --
// W2 pre-packed fragment-major (gnorm folded in): each B-frag = one coalesced
// 1KB wave load from L2-hot w2f. No LDS, no barrier -> latency-tolerant.
__global__ __launch_bounds__(256, 4) void k_gemm2g(const unsigned short* __restrict__ ybb,
                                                   const unsigned short* __restrict__ zb,
                                                   const unsigned short* __restrict__ w2f,
                                                   const float* __restrict__ xin,
                                                   float* __restrict__ out) {
    const int t = threadIdx.x;
    const int wave = t >> 6, lane = t & 63;
    const int fr = lane & 15, ko = lane >> 4;
    const int m0 = blockIdx.x * 64 + wave * 16;
    const size_t rowo = (size_t)(m0 + fr) * DI;
    float ss = 0.f;
    bf16x8 gb[8];
    #pragma unroll
    for (int kk = 0; kk < 8; kk++) {
        int co = kk * 32 + ko * 8;
        bf16x8 yv = *(const bf16x8*)(ybb + rowo + co);
        bf16x8 zv = *(const bf16x8*)(zb + rowo + co);
        #pragma unroll
        for (int j = 0; j < 8; j++) {
            float z = (float)zv[j];
            float g = (float)yv[j] * (z / (1.f + expf(-z)));
            ss += g * g;
            gb[kk][j] = (bf16)g;
        }
    }
    ss += __shfl_xor(ss, 16);
    ss += __shfl_xor(ss, 32);
    const float rs = rsqrtf(ss * (1.0f / DI) + EPSF);
    #pragma unroll
    for (int kk = 0; kk < 8; kk++)
        #pragma unroll
        for (int j = 0; j < 8; j++)
            gb[kk][j] = (bf16)((float)gb[kk][j] * rs);
    const unsigned short* wp = w2f + (size_t)lane * 8;
    f32x4 acc[8] = {};
    #pragma unroll
    for (int kk = 0; kk < 8; kk++) {
        #pragma unroll
        for (int nt = 0; nt < 8; nt++) {
            bf16x8 bfr = *(const bf16x8*)(wp + (((size_t)kk * 8 + nt) << 9));
            acc[nt] = __builtin_amdgcn_mfma_f32_16x16x32_bf16(gb[kk], bfr, acc[nt], 0, 0, 0);
        }
    }
    #pragma unroll
    for (int nt = 0; nt < 8; nt++) {
        int n = nt * 16 + fr;
        #pragma unroll
        for (int rr = 0; rr < 4; rr++) {
            int m = m0 + ko * 4 + rr;
            out[(size_t)m * DM + n] = xin[(size_t)m * DM + n] + acc[nt][rr];
        }
    }
}

extern "C" void kernel_launch(void* const* d_in, const int* in_sizes, int n_in,
                              void* d_out, int out_size, void* d_ws, size_t ws_size,
                              hipStream_t stream) {
    const float* x   = (const float*)d_in[0];
    const float* nw  = (const float*)d_in[1];
    const float* w1  = (const float*)d_in[2];
    const float* cw  = (const float*)d_in[3];
    const float* cb  = (const float*)d_in[4];
    const float* dtb = (const float*)d_in[5];
    const float* al  = (const float*)d_in[6];
    const float* Dw  = (const float*)d_in[7];
    const float* gw  = (const float*)d_in[8];
    const float* w2  = (const float*)d_in[9];
    float* out = (float*)d_out;

    float* ws = (float*)d_ws;
    float*  dAp = ws;                                   // 4096 fp32
    float*  dtf = dAp + NB * NH * NC;                   // NTOK*8 fp32
    unsigned short* hst = (unsigned short*)(dtf + (size_t)NTOK * NH); // 64*64*2048 bf16
    unsigned short* zb  = hst + (size_t)NB * NH * NC * 2048;          // NTOK*256
    unsigned short* xbc = zb + (size_t)NTOK * DI;                     // NTOK*384 (pre-conv)
    unsigned short* bcA = xbc + (size_t)NTOK * CDIM;                  // NTOK*128 (B|C tok-major)
    unsigned short* xT  = bcA + (size_t)NTOK * 128;                   // 256*NTOK (x ch-major)
    unsigned short* bT  = xT + (size_t)DI * NTOK;                     // 64*NTOK  (B ch-major)
    unsigned short* ybb = bT + (size_t)64 * NTOK;                     // NTOK*256
    unsigned short* w1b = ybb + (size_t)NTOK * DI;                    // 648*128
    unsigned short* w2f = w1b + (size_t)DPROJ * DM;                   // 128*256 frag-packed
    // alias (lifetimes disjoint): xnb dead before ssd3 writes ybb
    unsigned short* xnb = ybb;

    k_prep<<<(DPROJ * DM + DM * DI + 255) / 256, 256, 0, stream>>>(w1, w2, gw, w1b, w2f,
                                                                   DPROJ * DM);
    k_rmsdt<<<NTOK / 4, 256, 0, stream>>>(x, nw, w1, dtb, xnb, dtf);
    k_gemm1<<<dim3(NTOK / 64, 10), 256, 0, stream>>>(xnb, w1b, zb, xbc);
    k_conv<<<NTOK / 64, 384, 0, stream>>>(xbc, cw, cb, bcA, xT, bT);
    k_ssd1<<<NB * NH * (NC / 4), 256, 0, stream>>>(bT, xT, dtf, al, hst, dAp);
    k_ssm2<<<(NB * NH / 2) * 8, 256, 0, stream>>>(hst, dAp);
    k_ssd3<<<NB * NH * (NC / 4), 256, 0, stream>>>(bcA, xT, dtf, al, hst, Dw, ybb);
    k_gemm2g<<<NTOK / 64, 256, 0, stream>>>(ybb, zb, w2f, x, out);
}

// Round 3
// 197.074 us; speedup vs baseline: 1.0342x; 1.0342x over previous
//
#include <hip/hip_runtime.h>

#define DM    128
#define DI    256
#define NH    8
#define HD    32
#define NS    64
#define CDIM  384
#define DPROJ 648
#define LSEQ  4096
#define NB    8
#define NTOK  32768          // NB*LSEQ
#define LC    64             // chunk length
#define NC    64             // chunks per (b,h) sequence
#define EPSF  1e-5f
#define LOG2E 1.4426950408889634f

typedef __bf16 bf16;
typedef bf16  bf16x8 __attribute__((ext_vector_type(8)));
typedef bf16  bf16x4 __attribute__((ext_vector_type(4)));
typedef short short8 __attribute__((ext_vector_type(8)));
typedef float f32x4  __attribute__((ext_vector_type(4)));

__device__ __forceinline__ unsigned short f2bfbits(float f) {
    unsigned int u = __float_as_uint(f);
    unsigned int r = u + 0x7FFFu + ((u >> 16) & 1u);   // RNE
    return (unsigned short)(r >> 16);
}
__device__ __forceinline__ float bfbits2f(unsigned short u) {
    return __uint_as_float(((unsigned int)u) << 16);
}

// ---------------- 0. prep: W1 + W2 fragment-packs (gnorm folded into W2) -------
// Frag layout (both): frag f, lane l = ko*16+fr, elem j ->
//   row = base + fr, col k = kk*32 + ko*8 + j  (one coalesced 1KB load/wave).
// w1g: f = ns*4 + kk, ns = n/16 (n<640), from W1[n][k].
// w2f: f = kk*8 + nt, nt = n/16,          from W2[n][k]*gw[k].
__global__ __launch_bounds__(256) void k_prep(const float* __restrict__ w1,
                                              const float* __restrict__ w2,
                                              const float* __restrict__ gw,
                                              unsigned short* __restrict__ w1g,
                                              unsigned short* __restrict__ w2f) {
    int i = blockIdx.x * 256 + threadIdx.x;
    if (i < 640 * DM) {
        int f = i >> 9, r = i & 511;
        int lane = r >> 3, jj = r & 7;
        int ns = f >> 2, kk = f & 3;
        int n = ns * 16 + (lane & 15), k = kk * 32 + (lane >> 4) * 8 + jj;
        w1g[i] = f2bfbits(w1[(size_t)n * DM + k]);
    } else {
        int j = i - 640 * DM;
        if (j < DM * DI) {
            int f = j >> 9, r = j & 511;
            int lane = r >> 3, jj = r & 7;
            int kk = f >> 3, nt = f & 7;
            int fr = lane & 15, ko = lane >> 4;
            int n = nt * 16 + fr, k = kk * 32 + ko * 8 + jj;
            w2f[j] = f2bfbits(w2[(size_t)n * DI + k] * gw[k]);
        }
    }
}

// ---------------- 1. fused input RMSNorm + dt ----------------------------------
__global__ __launch_bounds__(256) void k_rmsdt(const float* __restrict__ x,
                                               const float* __restrict__ w,
                                               const float* __restrict__ w1,
                                               const float* __restrict__ dtb,
                                               unsigned short* __restrict__ xnb,
                                               float* __restrict__ dtf) {
    __shared__ float Xs[4][132];
    __shared__ float Wd[8][132];
    const int t = threadIdx.x;
    {
        int row = t >> 5, col = (t & 31) * 4;           // 8x128 = 256 float4
        *(float4*)&Wd[row][col] = *(const float4*)(w1 + (size_t)(640 + row) * DM + col);
    }
    const int wave = t >> 6, lane = t & 63;
    const size_t row = (size_t)blockIdx.x * 4 + wave;
    const float* xr = x + row * DM + lane * 2;
    float v0 = xr[0], v1 = xr[1];
    float ss = v0 * v0 + v1 * v1;
    #pragma unroll
    for (int o = 32; o; o >>= 1) ss += __shfl_xor(ss, o);
    float r = rsqrtf(ss * (1.0f / DM) + EPSF);
    float o0 = v0 * r * w[lane * 2], o1 = v1 * r * w[lane * 2 + 1];
    Xs[wave][lane * 2] = o0; Xs[wave][lane * 2 + 1] = o1;
    ushort2 ob; ob.x = f2bfbits(o0); ob.y = f2bfbits(o1);
    *(ushort2*)(xnb + row * DM + lane * 2) = ob;
    __syncthreads();
    const int h = lane >> 3, ks = lane & 7;
    float acc = 0.f;
    #pragma unroll
    for (int i = 0; i < 4; i++) {
        float4 xv = *(const float4*)&Xs[wave][ks * 16 + i * 4];
        float4 wv = *(const float4*)&Wd[h][ks * 16 + i * 4];
        acc = fmaf(xv.x, wv.x, acc);
        acc = fmaf(xv.y, wv.y, acc);
        acc = fmaf(xv.z, wv.z, acc);
        acc = fmaf(xv.w, wv.w, acc);
    }
    acc += __shfl_xor(acc, 1);
    acc += __shfl_xor(acc, 2);
    acc += __shfl_xor(acc, 4);
    if (ks == 0) {
        float v = acc + dtb[h];
        dtf[row * NH + h] = (v > 20.f) ? v : log1pf(expf(v));
    }
}

// ---------------- 2. GEMM1: no LDS, no barrier, frag-packed W1 -----------------
// A-frags (token-major xnb) held in 32 VGPRs across all 10 n-tiles; B-frags are
// coalesced 1KB wave loads from L2-hot w1g. grid = 512 blocks (A read once).
__global__ __launch_bounds__(256, 4) void k_gemm1(const unsigned short* __restrict__ A,
                                                  const unsigned short* __restrict__ w1g,
                                                  unsigned short* __restrict__ zb,
                                                  unsigned short* __restrict__ xbc) {
    const int t = threadIdx.x;
    const int m0 = blockIdx.x * 64;
    const int wave = t >> 6, lane = t & 63;
    const int wm = wave >> 1, wn = wave & 1;
    const int fr = lane & 15, ko = lane >> 4;
    bf16x8 a[2][4];
    #pragma unroll
    for (int mt = 0; mt < 2; mt++)
        #pragma unroll
        for (int kk = 0; kk < 4; kk++)
            a[mt][kk] = *(const bf16x8*)(A + (size_t)(m0 + wm * 32 + mt * 16 + fr) * DM
                                           + kk * 32 + ko * 8);
    for (int nt = 0; nt < 10; nt++) {
        const unsigned short* wb = w1g + (((size_t)(nt * 4 + wn * 2) * 4) << 9) + lane * 8;
        f32x4 acc[2][2] = {};
        #pragma unroll
        for (int kk = 0; kk < 4; kk++) {
            bf16x8 b0 = *(const bf16x8*)(wb + ((size_t)kk << 9));
            bf16x8 b1 = *(const bf16x8*)(wb + ((size_t)(4 + kk) << 9));
            acc[0][0] = __builtin_amdgcn_mfma_f32_16x16x32_bf16(a[0][kk], b0, acc[0][0], 0, 0, 0);
            acc[1][0] = __builtin_amdgcn_mfma_f32_16x16x32_bf16(a[1][kk], b0, acc[1][0], 0, 0, 0);
            acc[0][1] = __builtin_amdgcn_mfma_f32_16x16x32_bf16(a[0][kk], b1, acc[0][1], 0, 0, 0);
            acc[1][1] = __builtin_amdgcn_mfma_f32_16x16x32_bf16(a[1][kk], b1, acc[1][1], 0, 0, 0);
        }
        unsigned short* dst; int ld, nc0;
        if (nt < 4) { dst = zb;  ld = DI;   nc0 = nt * 64; }
        else        { dst = xbc; ld = CDIM; nc0 = nt * 64 - 256; }
        #pragma unroll
        for (int mt = 0; mt < 2; mt++)
            #pragma unroll
            for (int ntt = 0; ntt < 2; ntt++) {
                int n = nc0 + wn * 32 + ntt * 16 + fr;
                #pragma unroll
                for (int rr = 0; rr < 4; rr++) {
                    int m = m0 + wm * 32 + mt * 16 + ko * 4 + rr;
                    dst[(size_t)m * ld + n] = f2bfbits(acc[mt][ntt][rr]);
                }
            }
    }
}

// ---------------- 3. causal dw-conv (K=4) + SiLU; triple-layout output ---------
__global__ __launch_bounds__(384) void k_conv(const unsigned short* __restrict__ xbc,
                                              const float* __restrict__ cw,
                                              const float* __restrict__ cb,
                                              unsigned short* __restrict__ bcA,
                                              unsigned short* __restrict__ xT,
                                              unsigned short* __restrict__ bT) {
    __shared__ __align__(16) unsigned short L[320][72];
    const int c = threadIdx.x;
    const int t0 = blockIdx.x * 64;
    const int l0 = t0 & (LSEQ - 1);
    float4 wv = *(const float4*)(cw + c * 4);
    float bias = cb[c];
    const unsigned short* in = xbc + (size_t)t0 * CDIM + c;
    float h1 = 0.f, h2 = 0.f, h3 = 0.f;
    if (l0) {
        h1 = bfbits2f(in[-CDIM]);
        h2 = bfbits2f(in[-2 * CDIM]);
        h3 = bfbits2f(in[-3 * CDIM]);
    }
    short8 pk;
    #pragma unroll 8
    for (int t = 0; t < 64; t++) {
        float x0 = bfbits2f(in[(size_t)t * CDIM]);
        float acc = bias;
        acc = fmaf(x0, wv.w, acc);
        acc = fmaf(h1, wv.z, acc);
        acc = fmaf(h2, wv.y, acc);
        acc = fmaf(h3, wv.x, acc);
        float s = acc / (1.f + expf(-acc));
        unsigned short us = f2bfbits(s);
        if (c >= 256) bcA[(size_t)(t0 + t) * 128 + (c - 256)] = us;   // B|C token-major
        pk[t & 7] = (short)us;
        if (c < 320 && (t & 7) == 7) *(short8*)&L[c][t - 7] = pk;
        h3 = h2; h2 = h1; h1 = x0;
    }
    __syncthreads();
    #pragma unroll
    for (int it = 0; it < 7; it++) {
        int idx = it * 384 + c;
        if (idx < 2560) {                       // 320 rows x 8 token-chunks
            int row = idx >> 3, tc = (idx & 7) * 8;
            short8 v = *(const short8*)&L[row][tc];
            unsigned short* dst = (row < 256)
                ? xT + (size_t)row * NTOK + t0 + tc
                : bT + (size_t)(row - 256) * NTOK + t0 + tc;
            *(short8*)dst = v;
        }
    }
}

// ---------------- 5a. SSD pass 1: chunk-local end state, all-global frags ------
__global__ __launch_bounds__(256, 4) void k_ssd1(const unsigned short* __restrict__ bT,
                                                 const unsigned short* __restrict__ xT,
                                                 const float* __restrict__ dtf,
                                                 const float* __restrict__ alog,
                                                 unsigned short* __restrict__ hst,
                                                 float* __restrict__ dAp) {
    __shared__ __align__(16) float wl[4][64];
    const int bh = blockIdx.x >> 4, cg = blockIdx.x & 15;
    const int b = bh >> 3, h = bh & 7;
    const int wave = threadIdx.x >> 6, lane = threadIdx.x & 63;
    const int c = cg * 4 + wave;
    const size_t tok0 = (size_t)b * LSEQ + c * LC;
    const float A = -expf(alog[h]);
    float dt = dtf[(tok0 + lane) * NH + h];
    float q = dt * A * LOG2E;
    #pragma unroll
    for (int o = 1; o <= 32; o <<= 1) {
        float tmp = __shfl_up(q, o);
        if (lane >= o) q += tmp;
    }
    float qL = __shfl(q, 63);
    wl[wave][lane] = exp2f(qL - q) * dt;
    if (lane == 0) dAp[(size_t)bh * NC + c] = exp2f(qL);
    __syncthreads();
    const int m = lane & 15, ko = lane >> 4;
    f32x4 hacc[4][2] = {};
    #pragma unroll
    for (int kh = 0; kh < 2; kh++) {
        bf16x8 xb[2];
        #pragma unroll
        for (int pi = 0; pi < 2; pi++)
            xb[pi] = *(const bf16x8*)(xT + (size_t)(h * HD + pi * 16 + m) * NTOK + tok0 + kh * 32 + ko * 8);
        f32x4 w0 = *(const f32x4*)&wl[wave][kh * 32 + ko * 8];
        f32x4 w1 = *(const f32x4*)&wl[wave][kh * 32 + ko * 8 + 4];
        #pragma unroll
        for (int ni = 0; ni < 4; ni++) {
            bf16x8 bv = *(const bf16x8*)(bT + (size_t)(ni * 16 + m) * NTOK + tok0 + kh * 32 + ko * 8);
            bf16x8 af;
            #pragma unroll
            for (int j = 0; j < 4; j++) af[j] = (bf16)((float)bv[j] * w0[j]);
            #pragma unroll
            for (int j = 0; j < 4; j++) af[4 + j] = (bf16)((float)bv[4 + j] * w1[j]);
            #pragma unroll
            for (int pi = 0; pi < 2; pi++)
                hacc[ni][pi] = __builtin_amdgcn_mfma_f32_16x16x32_bf16(af, xb[pi], hacc[ni][pi], 0, 0, 0);
        }
    }
    unsigned short* hb = hst + (((size_t)bh * NC + c) << 11);
    #pragma unroll
    for (int ni = 0; ni < 4; ni++)
        #pragma unroll
        for (int pi = 0; pi < 2; pi++) {
            bf16x4 pv;
            #pragma unroll
            for (int r = 0; r < 4; r++) pv[r] = (bf16)hacc[ni][pi][r];
            *(bf16x4*)(hb + (pi * 16 + m) * 64 + ni * 16 + ko * 4) = pv;
        }
}

// ---------------- 5b. SSM pass 2: scan, 1 bh/block, depth-4 load pipeline ------
__global__ __launch_bounds__(256) void k_ssm2(unsigned short* __restrict__ hst,
                                              const float* __restrict__ dAp) {
    __shared__ float dl[NC];
    const int bh = blockIdx.x >> 3, seg = blockIdx.x & 7;
    const int s = seg * 256 + threadIdx.x;
    if (threadIdx.x < NC) dl[threadIdx.x] = dAp[(size_t)bh * NC + threadIdx.x];
    __syncthreads();
    unsigned short* p = hst + ((size_t)bh * NC << 11) + s;
    float r = 0.f;
    float v0 = bfbits2f(p[0]);
    float v1 = bfbits2f(p[(size_t)1 << 11]);
    float v2 = bfbits2f(p[(size_t)2 << 11]);
    float v3 = bfbits2f(p[(size_t)3 << 11]);
    for (int c = 0; c < NC; c += 4) {
        float t;
        t = v0; if (c + 4 < NC) v0 = bfbits2f(p[(size_t)(c + 4) << 11]);
        p[(size_t)c << 11] = f2bfbits(r);       r = fmaf(r, dl[c], t);
        t = v1; if (c + 5 < NC) v1 = bfbits2f(p[(size_t)(c + 5) << 11]);
        p[(size_t)(c + 1) << 11] = f2bfbits(r); r = fmaf(r, dl[c + 1], t);
        t = v2; if (c + 6 < NC) v2 = bfbits2f(p[(size_t)(c + 6) << 11]);
        p[(size_t)(c + 2) << 11] = f2bfbits(r); r = fmaf(r, dl[c + 2], t);
        t = v3; if (c + 7 < NC) v3 = bfbits2f(p[(size_t)(c + 7) << 11]);
        p[(size_t)(c + 3) << 11] = f2bfbits(r); r = fmaf(r, dl[c + 3], t);
    }
}

// ---------------- 5c. SSD pass 3: Y = P.X + diag(2^q).(C.h_in^T) ---------------
__global__ __launch_bounds__(256, 2) void k_ssd3(const unsigned short* __restrict__ bcA,
                                                 const unsigned short* __restrict__ xT,
                                                 const float* __restrict__ dtf,
                                                 const float* __restrict__ alog,
                                                 const unsigned short* __restrict__ hst,
                                                 const float* __restrict__ Dw,
                                                 unsigned short* __restrict__ ybb) {
    __shared__ __align__(16) bf16 Pl[4][64 * 72];
    __shared__ __align__(16) float ql[4][64];
    __shared__ __align__(16) float dl[4][64];
    const int bh = blockIdx.x >> 4, cg = blockIdx.x & 15;
    const int b = bh >> 3, h = bh & 7;
    const int wave = threadIdx.x >> 6, lane = threadIdx.x & 63;
    const int c = cg * 4 + wave;
    const size_t tok0 = (size_t)b * LSEQ + c * LC;
    const float A = -expf(alog[h]);
    const float Dh = Dw[h];
    float dt = dtf[(tok0 + lane) * NH + h];
    float q = dt * A * LOG2E;
    #pragma unroll
    for (int o = 1; o <= 32; o <<= 1) {
        float tmp = __shfl_up(q, o);
        if (lane >= o) q += tmp;
    }
    ql[wave][lane] = q;
    dl[wave][lane] = dt;
    const int m = lane & 15, ko = lane >> 4;
    bf16x8 cf[4][2];
    #pragma unroll
    for (int ti = 0; ti < 4; ti++)
        #pragma unroll
        for (int kh = 0; kh < 2; kh++)
            cf[ti][kh] = *(const bf16x8*)(bcA + (tok0 + ti * 16 + m) * 128 + 64 + kh * 32 + ko * 8);
    f32x4 gt[4][4] = {};
    #pragma unroll
    for (int kh = 0; kh < 2; kh++) {
        bf16x8 bfg[4];
        #pragma unroll
        for (int si = 0; si < 4; si++)
            bfg[si] = *(const bf16x8*)(bcA + (tok0 + si * 16 + m) * 128 + kh * 32 + ko * 8);
        #pragma unroll
        for (int ti = 0; ti < 4; ti++)
            #pragma unroll
            for (int si = 0; si < 4; si++)
                gt[ti][si] = __builtin_amdgcn_mfma_f32_16x16x32_bf16(bfg[si], cf[ti][kh], gt[ti][si], 0, 0, 0);
    }
    __syncthreads();
    float qt[4];
    #pragma unroll
    for (int ti = 0; ti < 4; ti++) qt[ti] = ql[wave][ti * 16 + m];
    #pragma unroll
    for (int si = 0; si < 4; si++) {
        f32x4 qs = *(const f32x4*)&ql[wave][si * 16 + ko * 4];
        f32x4 ds = *(const f32x4*)&dl[wave][si * 16 + ko * 4];
        #pragma unroll
        for (int ti = 0; ti < 4; ti++) {
            bf16x4 pv = {};
            if (si <= ti) {
                const int t = ti * 16 + m;
                #pragma unroll
                for (int r = 0; r < 4; r++) {
                    int s = si * 16 + ko * 4 + r;
                    float p = 0.f;
                    if (s <= t) {
                        p = exp2f(qt[ti] - qs[r]) * ds[r] * gt[ti][si][r];
                        if (s == t) p += Dh;
                    }
                    pv[r] = (bf16)p;
                }
            }
            *(bf16x4*)&Pl[wave][(ti * 16 + m) * 72 + si * 16 + ko * 4] = pv;
        }
    }
    __syncthreads();
    f32x4 et[4];
    #pragma unroll
    for (int ti = 0; ti < 4; ti++) {
        f32x4 qv = *(const f32x4*)&ql[wave][ti * 16 + ko * 4];
        #pragma unroll
        for (int r = 0; r < 4; r++) et[ti][r] = exp2f(qv[r]);
    }
    const size_t hbase = ((size_t)bh * NC + c) << 11;
    f32x4 ya[4][2] = {}, ua[4][2] = {};
    #pragma unroll
    for (int kh = 0; kh < 2; kh++) {
        bf16x8 xb[2], hb2[2];
        #pragma unroll
        for (int pi = 0; pi < 2; pi++) {
            xb[pi]  = *(const bf16x8*)(xT + (size_t)(h * HD + pi * 16 + m) * NTOK + tok0 + kh * 32 + ko * 8);
            hb2[pi] = *(const bf16x8*)(hst + hbase + (pi * 16 + m) * 64 + kh * 32 + ko * 8);
        }
        #pragma unroll
        for (int ti = 0; ti < 4; ti++) {
            bf16x8 pa = *(const bf16x8*)&Pl[wave][(ti * 16 + m) * 72 + kh * 32 + ko * 8];
            #pragma unroll
            for (int pi = 0; pi < 2; pi++) {
                ya[ti][pi] = __builtin_amdgcn_mfma_f32_16x16x32_bf16(pa, xb[pi], ya[ti][pi], 0, 0, 0);
                ua[ti][pi] = __builtin_amdgcn_mfma_f32_16x16x32_bf16(cf[ti][kh], hb2[pi], ua[ti][pi], 0, 0, 0);
            }
        }
    }
    unsigned short* yrow = ybb + tok0 * DI + h * HD;
    #pragma unroll
    for (int ti = 0; ti < 4; ti++)
        #pragma unroll
        for (int pi = 0; pi < 2; pi++)
            #pragma unroll
            for (int r = 0; r < 4; r++) {
                int t = ti * 16 + ko * 4 + r;
                yrow[(size_t)t * DI + pi * 16 + m] =
                    f2bfbits(ya[ti][pi][r] + et[ti][r] * ua[ti][pi][r]);
            }
}

// ---------------- 6+7. fused gate + GEMM2 + residual (no LDS, frag-packed W2) --
__global__ __launch_bounds__(256, 4) void k_gemm2g(const unsigned short* __restrict__ ybb,
                                                   const unsigned short* __restrict__ zb,
                                                   const unsigned short* __restrict__ w2f,
                                                   const float* __restrict__ xin,
                                                   float* __restrict__ out) {
    const int t = threadIdx.x;
    const int wave = t >> 6, lane = t & 63;
    const int fr = lane & 15, ko = lane >> 4;
    const int m0 = blockIdx.x * 64 + wave * 16;
    const size_t rowo = (size_t)(m0 + fr) * DI;
    float ss = 0.f;
    bf16x8 gb[8];
    #pragma unroll
    for (int kk = 0; kk < 8; kk++) {
        int co = kk * 32 + ko * 8;
        bf16x8 yv = *(const bf16x8*)(ybb + rowo + co);
        bf16x8 zv = *(const bf16x8*)(zb + rowo + co);
        #pragma unroll
        for (int j = 0; j < 8; j++) {
            float z = (float)zv[j];
            float g = (float)yv[j] * (z / (1.f + expf(-z)));
            ss += g * g;
            gb[kk][j] = (bf16)g;
        }
    }
    ss += __shfl_xor(ss, 16);
    ss += __shfl_xor(ss, 32);
    const float rs = rsqrtf(ss * (1.0f / DI) + EPSF);
    #pragma unroll
    for (int kk = 0; kk < 8; kk++)
        #pragma unroll
        for (int j = 0; j < 8; j++)
            gb[kk][j] = (bf16)((float)gb[kk][j] * rs);
    const unsigned short* wp = w2f + (size_t)lane * 8;
    f32x4 acc[8] = {};
    #pragma unroll
    for (int kk = 0; kk < 8; kk++) {
        #pragma unroll
        for (int nt = 0; nt < 8; nt++) {
            bf16x8 bfr = *(const bf16x8*)(wp + (((size_t)kk * 8 + nt) << 9));
            acc[nt] = __builtin_amdgcn_mfma_f32_16x16x32_bf16(gb[kk], bfr, acc[nt], 0, 0, 0);
        }
    }
    #pragma unroll
    for (int nt = 0; nt < 8; nt++) {
        int n = nt * 16 + fr;
        #pragma unroll
        for (int rr = 0; rr < 4; rr++) {
            int m = m0 + ko * 4 + rr;
            out[(size_t)m * DM + n] = xin[(size_t)m * DM + n] + acc[nt][rr];
        }
    }
}

extern "C" void kernel_launch(void* const* d_in, const int* in_sizes, int n_in,
                              void* d_out, int out_size, void* d_ws, size_t ws_size,
                              hipStream_t stream) {
    const float* x   = (const float*)d_in[0];
    const float* nw  = (const float*)d_in[1];
    const float* w1  = (const float*)d_in[2];
    const float* cw  = (const float*)d_in[3];
    const float* cb  = (const float*)d_in[4];
    const float* dtb = (const float*)d_in[5];
    const float* al  = (const float*)d_in[6];
    const float* Dw  = (const float*)d_in[7];
    const float* gw  = (const float*)d_in[8];
    const float* w2  = (const float*)d_in[9];
    float* out = (float*)d_out;

    float* ws = (float*)d_ws;
    float*  dAp = ws;                                   // 4096 fp32
    float*  dtf = dAp + NB * NH * NC;                   // NTOK*8 fp32
    unsigned short* hst = (unsigned short*)(dtf + (size_t)NTOK * NH); // 64*64*2048 bf16
    unsigned short* zb  = hst + (size_t)NB * NH * NC * 2048;          // NTOK*256
    unsigned short* xbc = zb + (size_t)NTOK * DI;                     // NTOK*384 (pre-conv)
    unsigned short* bcA = xbc + (size_t)NTOK * CDIM;                  // NTOK*128 (B|C tok-major)
    unsigned short* xT  = bcA + (size_t)NTOK * 128;                   // 256*NTOK (x ch-major)
    unsigned short* bT  = xT + (size_t)DI * NTOK;                     // 64*NTOK  (B ch-major)
    unsigned short* ybb = bT + (size_t)64 * NTOK;                     // NTOK*256
    unsigned short* w1g = ybb + (size_t)NTOK * DI;                    // 640*128 frag-packed
    unsigned short* w2f = w1g + (size_t)640 * DM;                     // 128*256 frag-packed
    // alias (lifetimes disjoint): xnb dead before ssd3 writes ybb
    unsigned short* xnb = ybb;

    k_prep<<<(640 * DM + DM * DI + 255) / 256, 256, 0, stream>>>(w1, w2, gw, w1g, w2f);
    k_rmsdt<<<NTOK / 4, 256, 0, stream>>>(x, nw, w1, dtb, xnb, dtf);
    k_gemm1<<<NTOK / 64, 256, 0, stream>>>(xnb, w1g, zb, xbc);
    k_conv<<<NTOK / 64, 384, 0, stream>>>(xbc, cw, cb, bcA, xT, bT);
    k_ssd1<<<NB * NH * (NC / 4), 256, 0, stream>>>(bT, xT, dtf, al, hst, dAp);
    k_ssm2<<<NB * NH * 8, 256, 0, stream>>>(hst, dAp);
    k_ssd3<<<NB * NH * (NC / 4), 256, 0, stream>>>(bcA, xT, dtf, al, hst, Dw, ybb);
    k_gemm2g<<<NTOK / 64, 256, 0, stream>>>(ybb, zb, w2f, x, out);
}

// Round 4
// 194.236 us; speedup vs baseline: 1.0493x; 1.0146x over previous
//
#include <hip/hip_runtime.h>

#define DM    128
#define DI    256
#define NH    8
#define HD    32
#define NS    64
#define CDIM  384
#define DPROJ 648
#define LSEQ  4096
#define NB    8
#define NTOK  32768          // NB*LSEQ
#define LC    64             // chunk length
#define NC    64             // chunks per (b,h) sequence
#define EPSF  1e-5f
#define LOG2E 1.4426950408889634f

typedef __bf16 bf16;
typedef bf16  bf16x8 __attribute__((ext_vector_type(8)));
typedef bf16  bf16x4 __attribute__((ext_vector_type(4)));
typedef short short8 __attribute__((ext_vector_type(8)));
typedef float f32x4  __attribute__((ext_vector_type(4)));

__device__ __forceinline__ unsigned short f2bfbits(float f) {
    unsigned int u = __float_as_uint(f);
    unsigned int r = u + 0x7FFFu + ((u >> 16) & 1u);   // RNE
    return (unsigned short)(r >> 16);
}
__device__ __forceinline__ float bfbits2f(unsigned short u) {
    return __uint_as_float(((unsigned int)u) << 16);
}

// ---------------- 0. prep: W1 + W2 fragment-packs (gnorm folded into W2) -------
// Frag layout (both): frag f, lane l = ko*16+fr, elem j ->
//   row = base + fr, col k = kk*32 + ko*8 + j  (one coalesced 1KB load/wave).
// w1g: f = ns*4 + kk, ns = n/16 (n<640), from W1[n][k].
// w2f: f = kk*8 + nt, nt = n/16,          from W2[n][k]*gw[k].
__global__ __launch_bounds__(256) void k_prep(const float* __restrict__ w1,
                                              const float* __restrict__ w2,
                                              const float* __restrict__ gw,
                                              unsigned short* __restrict__ w1g,
                                              unsigned short* __restrict__ w2f) {
    int i = blockIdx.x * 256 + threadIdx.x;
    if (i < 640 * DM) {
        int f = i >> 9, r = i & 511;
        int lane = r >> 3, jj = r & 7;
        int ns = f >> 2, kk = f & 3;
        int n = ns * 16 + (lane & 15), k = kk * 32 + (lane >> 4) * 8 + jj;
        w1g[i] = f2bfbits(w1[(size_t)n * DM + k]);
    } else {
        int j = i - 640 * DM;
        if (j < DM * DI) {
            int f = j >> 9, r = j & 511;
            int lane = r >> 3, jj = r & 7;
            int kk = f >> 3, nt = f & 7;
            int fr = lane & 15, ko = lane >> 4;
            int n = nt * 16 + fr, k = kk * 32 + ko * 8 + jj;
            w2f[j] = f2bfbits(w2[(size_t)n * DI + k] * gw[k]);
        }
    }
}

// ---------------- 1+2. fused RMSNorm + dt + GEMM1 (frag-packed W1, no xnb) -----
// Phase 1: each wave rmsnorms its 16 rows into fp32 LDS tile Xs.
// Phase 2a: dt via exact fp32 dot (same math as the old k_rmsdt) + softplus.
// Phase 2b: bf16 A-frags built from Xs; then the barrier-free 10-n-tile loop
// with coalesced 1KB B-frag loads from L2-hot w1g.
__global__ __launch_bounds__(256, 4) void k_gemm1(const float* __restrict__ x,
                                                  const float* __restrict__ nw,
                                                  const float* __restrict__ w1,
                                                  const float* __restrict__ dtb,
                                                  const unsigned short* __restrict__ w1g,
                                                  unsigned short* __restrict__ zb,
                                                  unsigned short* __restrict__ xbc,
                                                  float* __restrict__ dtf) {
    __shared__ float Xs[64][132];
    __shared__ float Wd[8][132];
    const int t = threadIdx.x;
    const int wave = t >> 6, lane = t & 63;
    const int m0 = blockIdx.x * 64;
    {   // stage dt weight rows (w1[640..647]) once
        int row = t >> 5, col = (t & 31) * 4;
        *(float4*)&Wd[row][col] = *(const float4*)(w1 + (size_t)(640 + row) * DM + col);
    }
    // phase 1: rmsnorm 16 rows per wave -> fp32 LDS
    const float nw0 = nw[lane * 2], nw1 = nw[lane * 2 + 1];
    #pragma unroll
    for (int i = 0; i < 16; i++) {
        int r = wave * 16 + i;
        const float* xr = x + (size_t)(m0 + r) * DM + lane * 2;
        float v0 = xr[0], v1 = xr[1];
        float ss = v0 * v0 + v1 * v1;
        #pragma unroll
        for (int o = 32; o; o >>= 1) ss += __shfl_xor(ss, o);
        float rs = rsqrtf(ss * (1.0f / DM) + EPSF);
        Xs[r][lane * 2]     = v0 * rs * nw0;
        Xs[r][lane * 2 + 1] = v1 * rs * nw1;
    }
    __syncthreads();
    // phase 2a: dt (fp32 exact) for this wave's 16 rows
    {
        const int h = lane >> 3, ks = lane & 7;
        const float dtbh = dtb[h];
        #pragma unroll
        for (int i = 0; i < 16; i++) {
            int r = wave * 16 + i;
            float acc = 0.f;
            #pragma unroll
            for (int q = 0; q < 4; q++) {
                float4 xv = *(const float4*)&Xs[r][ks * 16 + q * 4];
                float4 wv = *(const float4*)&Wd[h][ks * 16 + q * 4];
                acc = fmaf(xv.x, wv.x, acc); acc = fmaf(xv.y, wv.y, acc);
                acc = fmaf(xv.z, wv.z, acc); acc = fmaf(xv.w, wv.w, acc);
            }
            acc += __shfl_xor(acc, 1);
            acc += __shfl_xor(acc, 2);
            acc += __shfl_xor(acc, 4);
            if (ks == 0) {
                float v = acc + dtbh;
                dtf[(size_t)(m0 + r) * NH + h] = (v > 20.f) ? v : log1pf(expf(v));
            }
        }
    }
    // phase 2b: bf16 A-frags from Xs
    const int wm = wave >> 1, wn = wave & 1;
    const int fr = lane & 15, ko = lane >> 4;
    bf16x8 a[2][4];
    #pragma unroll
    for (int mt = 0; mt < 2; mt++)
        #pragma unroll
        for (int kk = 0; kk < 4; kk++) {
            const float* src = &Xs[wm * 32 + mt * 16 + fr][kk * 32 + ko * 8];
            float4 lo = *(const float4*)src, hi = *(const float4*)(src + 4);
            bf16x8 af;
            af[0] = (bf16)lo.x; af[1] = (bf16)lo.y; af[2] = (bf16)lo.z; af[3] = (bf16)lo.w;
            af[4] = (bf16)hi.x; af[5] = (bf16)hi.y; af[6] = (bf16)hi.z; af[7] = (bf16)hi.w;
            a[mt][kk] = af;
        }
    // n-tile loop: 10 x 64 cols, B-frags = coalesced 1KB wave loads
    for (int nt = 0; nt < 10; nt++) {
        const unsigned short* wb = w1g + (((size_t)(nt * 4 + wn * 2) * 4) << 9) + lane * 8;
        f32x4 acc[2][2] = {};
        #pragma unroll
        for (int kk = 0; kk < 4; kk++) {
            bf16x8 b0 = *(const bf16x8*)(wb + ((size_t)kk << 9));
            bf16x8 b1 = *(const bf16x8*)(wb + ((size_t)(4 + kk) << 9));
            acc[0][0] = __builtin_amdgcn_mfma_f32_16x16x32_bf16(a[0][kk], b0, acc[0][0], 0, 0, 0);
            acc[1][0] = __builtin_amdgcn_mfma_f32_16x16x32_bf16(a[1][kk], b0, acc[1][0], 0, 0, 0);
            acc[0][1] = __builtin_amdgcn_mfma_f32_16x16x32_bf16(a[0][kk], b1, acc[0][1], 0, 0, 0);
            acc[1][1] = __builtin_amdgcn_mfma_f32_16x16x32_bf16(a[1][kk], b1, acc[1][1], 0, 0, 0);
        }
        unsigned short* dst; int ld, nc0;
        if (nt < 4) { dst = zb;  ld = DI;   nc0 = nt * 64; }
        else        { dst = xbc; ld = CDIM; nc0 = nt * 64 - 256; }
        #pragma unroll
        for (int mt = 0; mt < 2; mt++)
            #pragma unroll
            for (int ntt = 0; ntt < 2; ntt++) {
                int n = nc0 + wn * 32 + ntt * 16 + fr;
                #pragma unroll
                for (int rr = 0; rr < 4; rr++) {
                    int m = m0 + wm * 32 + mt * 16 + ko * 4 + rr;
                    dst[(size_t)m * ld + n] = f2bfbits(acc[mt][ntt][rr]);
                }
            }
    }
}

// ---------------- 3. causal dw-conv (K=4) + SiLU; triple-layout output ---------
__global__ __launch_bounds__(384) void k_conv(const unsigned short* __restrict__ xbc,
                                              const float* __restrict__ cw,
                                              const float* __restrict__ cb,
                                              unsigned short* __restrict__ bcA,
                                              unsigned short* __restrict__ xT,
                                              unsigned short* __restrict__ bT) {
    __shared__ __align__(16) unsigned short L[320][72];
    const int c = threadIdx.x;
    const int t0 = blockIdx.x * 64;
    const int l0 = t0 & (LSEQ - 1);
    float4 wv = *(const float4*)(cw + c * 4);
    float bias = cb[c];
    const unsigned short* in = xbc + (size_t)t0 * CDIM + c;
    float h1 = 0.f, h2 = 0.f, h3 = 0.f;
    if (l0) {
        h1 = bfbits2f(in[-CDIM]);
        h2 = bfbits2f(in[-2 * CDIM]);
        h3 = bfbits2f(in[-3 * CDIM]);
    }
    short8 pk;
    #pragma unroll 8
    for (int t = 0; t < 64; t++) {
        float x0 = bfbits2f(in[(size_t)t * CDIM]);
        float acc = bias;
        acc = fmaf(x0, wv.w, acc);
        acc = fmaf(h1, wv.z, acc);
        acc = fmaf(h2, wv.y, acc);
        acc = fmaf(h3, wv.x, acc);
        float s = acc / (1.f + expf(-acc));
        unsigned short us = f2bfbits(s);
        if (c >= 256) bcA[(size_t)(t0 + t) * 128 + (c - 256)] = us;   // B|C token-major
        pk[t & 7] = (short)us;
        if (c < 320 && (t & 7) == 7) *(short8*)&L[c][t - 7] = pk;
        h3 = h2; h2 = h1; h1 = x0;
    }
    __syncthreads();
    #pragma unroll
    for (int it = 0; it < 7; it++) {
        int idx = it * 384 + c;
        if (idx < 2560) {                       // 320 rows x 8 token-chunks
            int row = idx >> 3, tc = (idx & 7) * 8;
            short8 v = *(const short8*)&L[row][tc];
            unsigned short* dst = (row < 256)
                ? xT + (size_t)row * NTOK + t0 + tc
                : bT + (size_t)(row - 256) * NTOK + t0 + tc;
            *(short8*)dst = v;
        }
    }
}

// ---------------- 5a. SSD pass 1: chunk-local end state, all-global frags ------
// All LDS traffic is intra-wave (wl[wave]) -> NO barrier needed (lgkmcnt orders).
__global__ __launch_bounds__(256, 4) void k_ssd1(const unsigned short* __restrict__ bT,
                                                 const unsigned short* __restrict__ xT,
                                                 const float* __restrict__ dtf,
                                                 const float* __restrict__ alog,
                                                 unsigned short* __restrict__ hst,
                                                 float* __restrict__ dAp) {
    __shared__ __align__(16) float wl[4][64];
    const int bh = blockIdx.x >> 4, cg = blockIdx.x & 15;
    const int b = bh >> 3, h = bh & 7;
    const int wave = threadIdx.x >> 6, lane = threadIdx.x & 63;
    const int c = cg * 4 + wave;
    const size_t tok0 = (size_t)b * LSEQ + c * LC;
    const float A = -expf(alog[h]);
    float dt = dtf[(tok0 + lane) * NH + h];
    float q = dt * A * LOG2E;
    #pragma unroll
    for (int o = 1; o <= 32; o <<= 1) {
        float tmp = __shfl_up(q, o);
        if (lane >= o) q += tmp;
    }
    float qL = __shfl(q, 63);
    wl[wave][lane] = exp2f(qL - q) * dt;
    if (lane == 0) dAp[(size_t)bh * NC + c] = exp2f(qL);
    const int m = lane & 15, ko = lane >> 4;
    f32x4 hacc[4][2] = {};
    #pragma unroll
    for (int kh = 0; kh < 2; kh++) {
        bf16x8 xb[2];
        #pragma unroll
        for (int pi = 0; pi < 2; pi++)
            xb[pi] = *(const bf16x8*)(xT + (size_t)(h * HD + pi * 16 + m) * NTOK + tok0 + kh * 32 + ko * 8);
        f32x4 w0 = *(const f32x4*)&wl[wave][kh * 32 + ko * 8];
        f32x4 w1 = *(const f32x4*)&wl[wave][kh * 32 + ko * 8 + 4];
        #pragma unroll
        for (int ni = 0; ni < 4; ni++) {
            bf16x8 bv = *(const bf16x8*)(bT + (size_t)(ni * 16 + m) * NTOK + tok0 + kh * 32 + ko * 8);
            bf16x8 af;
            #pragma unroll
            for (int j = 0; j < 4; j++) af[j] = (bf16)((float)bv[j] * w0[j]);
            #pragma unroll
            for (int j = 0; j < 4; j++) af[4 + j] = (bf16)((float)bv[4 + j] * w1[j]);
            #pragma unroll
            for (int pi = 0; pi < 2; pi++)
                hacc[ni][pi] = __builtin_amdgcn_mfma_f32_16x16x32_bf16(af, xb[pi], hacc[ni][pi], 0, 0, 0);
        }
    }
    unsigned short* hb = hst + (((size_t)bh * NC + c) << 11);
    #pragma unroll
    for (int ni = 0; ni < 4; ni++)
        #pragma unroll
        for (int pi = 0; pi < 2; pi++) {
            bf16x4 pv;
            #pragma unroll
            for (int r = 0; r < 4; r++) pv[r] = (bf16)hacc[ni][pi][r];
            *(bf16x4*)(hb + (pi * 16 + m) * 64 + ni * 16 + ko * 4) = pv;
        }
}

// ---------------- 5b. SSM pass 2: scan, 1 bh/block, depth-4 load pipeline ------
__global__ __launch_bounds__(256) void k_ssm2(unsigned short* __restrict__ hst,
                                              const float* __restrict__ dAp) {
    __shared__ float dl[NC];
    const int bh = blockIdx.x >> 3, seg = blockIdx.x & 7;
    const int s = seg * 256 + threadIdx.x;
    if (threadIdx.x < NC) dl[threadIdx.x] = dAp[(size_t)bh * NC + threadIdx.x];
    __syncthreads();
    unsigned short* p = hst + ((size_t)bh * NC << 11) + s;
    float r = 0.f;
    float v0 = bfbits2f(p[0]);
    float v1 = bfbits2f(p[(size_t)1 << 11]);
    float v2 = bfbits2f(p[(size_t)2 << 11]);
    float v3 = bfbits2f(p[(size_t)3 << 11]);
    for (int c = 0; c < NC; c += 4) {
        float t;
        t = v0; if (c + 4 < NC) v0 = bfbits2f(p[(size_t)(c + 4) << 11]);
        p[(size_t)c << 11] = f2bfbits(r);       r = fmaf(r, dl[c], t);
        t = v1; if (c + 5 < NC) v1 = bfbits2f(p[(size_t)(c + 5) << 11]);
        p[(size_t)(c + 1) << 11] = f2bfbits(r); r = fmaf(r, dl[c + 1], t);
        t = v2; if (c + 6 < NC) v2 = bfbits2f(p[(size_t)(c + 6) << 11]);
        p[(size_t)(c + 2) << 11] = f2bfbits(r); r = fmaf(r, dl[c + 2], t);
        t = v3; if (c + 7 < NC) v3 = bfbits2f(p[(size_t)(c + 7) << 11]);
        p[(size_t)(c + 3) << 11] = f2bfbits(r); r = fmaf(r, dl[c + 3], t);
    }
}

// ---------------- 5c. SSD pass 3: Y = P.X + diag(2^q).(C.h_in^T) ---------------
// All LDS buffers (ql, dl, Pl) are [wave]-indexed -> intra-wave only, NO
// barriers (compiler lgkmcnt orders ds_write -> ds_read within the wave).
__global__ __launch_bounds__(256, 2) void k_ssd3(const unsigned short* __restrict__ bcA,
                                                 const unsigned short* __restrict__ xT,
                                                 const float* __restrict__ dtf,
                                                 const float* __restrict__ alog,
                                                 const unsigned short* __restrict__ hst,
                                                 const float* __restrict__ Dw,
                                                 unsigned short* __restrict__ ybb) {
    __shared__ __align__(16) bf16 Pl[4][64 * 72];
    __shared__ __align__(16) float ql[4][64];
    __shared__ __align__(16) float dl[4][64];
    const int bh = blockIdx.x >> 4, cg = blockIdx.x & 15;
    const int b = bh >> 3, h = bh & 7;
    const int wave = threadIdx.x >> 6, lane = threadIdx.x & 63;
    const int c = cg * 4 + wave;
    const size_t tok0 = (size_t)b * LSEQ + c * LC;
    const float A = -expf(alog[h]);
    const float Dh = Dw[h];
    float dt = dtf[(tok0 + lane) * NH + h];
    float q = dt * A * LOG2E;
    #pragma unroll
    for (int o = 1; o <= 32; o <<= 1) {
        float tmp = __shfl_up(q, o);
        if (lane >= o) q += tmp;
    }
    ql[wave][lane] = q;
    dl[wave][lane] = dt;
    const int m = lane & 15, ko = lane >> 4;
    bf16x8 cf[4][2];
    #pragma unroll
    for (int ti = 0; ti < 4; ti++)
        #pragma unroll
        for (int kh = 0; kh < 2; kh++)
            cf[ti][kh] = *(const bf16x8*)(bcA + (tok0 + ti * 16 + m) * 128 + 64 + kh * 32 + ko * 8);
    f32x4 gt[4][4] = {};
    #pragma unroll
    for (int kh = 0; kh < 2; kh++) {
        bf16x8 bfg[4];
        #pragma unroll
        for (int si = 0; si < 4; si++)
            bfg[si] = *(const bf16x8*)(bcA + (tok0 + si * 16 + m) * 128 + kh * 32 + ko * 8);
        #pragma unroll
        for (int ti = 0; ti < 4; ti++)
            #pragma unroll
            for (int si = 0; si < 4; si++)
                gt[ti][si] = __builtin_amdgcn_mfma_f32_16x16x32_bf16(bfg[si], cf[ti][kh], gt[ti][si], 0, 0, 0);
    }
    float qt[4];
    #pragma unroll
    for (int ti = 0; ti < 4; ti++) qt[ti] = ql[wave][ti * 16 + m];
    #pragma unroll
    for (int si = 0; si < 4; si++) {
        f32x4 qs = *(const f32x4*)&ql[wave][si * 16 + ko * 4];
        f32x4 ds = *(const f32x4*)&dl[wave][si * 16 + ko * 4];
        #pragma unroll
        for (int ti = 0; ti < 4; ti++) {
            bf16x4 pv = {};
            if (si <= ti) {
                const int t = ti * 16 + m;
                #pragma unroll
                for (int r = 0; r < 4; r++) {
                    int s = si * 16 + ko * 4 + r;
                    float p = 0.f;
                    if (s <= t) {
                        p = exp2f(qt[ti] - qs[r]) * ds[r] * gt[ti][si][r];
                        if (s == t) p += Dh;
                    }
                    pv[r] = (bf16)p;
                }
            }
            *(bf16x4*)&Pl[wave][(ti * 16 + m) * 72 + si * 16 + ko * 4] = pv;
        }
    }
    f32x4 et[4];
    #pragma unroll
    for (int ti = 0; ti < 4; ti++) {
        f32x4 qv = *(const f32x4*)&ql[wave][ti * 16 + ko * 4];
        #pragma unroll
        for (int r = 0; r < 4; r++) et[ti][r] = exp2f(qv[r]);
    }
    const size_t hbase = ((size_t)bh * NC + c) << 11;
    f32x4 ya[4][2] = {}, ua[4][2] = {};
    #pragma unroll
    for (int kh = 0; kh < 2; kh++) {
        bf16x8 xb[2], hb2[2];
        #pragma unroll
        for (int pi = 0; pi < 2; pi++) {
            xb[pi]  = *(const bf16x8*)(xT + (size_t)(h * HD + pi * 16 + m) * NTOK + tok0 + kh * 32 + ko * 8);
            hb2[pi] = *(const bf16x8*)(hst + hbase + (pi * 16 + m) * 64 + kh * 32 + ko * 8);
        }
        #pragma unroll
        for (int ti = 0; ti < 4; ti++) {
            bf16x8 pa = *(const bf16x8*)&Pl[wave][(ti * 16 + m) * 72 + kh * 32 + ko * 8];
            #pragma unroll
            for (int pi = 0; pi < 2; pi++) {
                ya[ti][pi] = __builtin_amdgcn_mfma_f32_16x16x32_bf16(pa, xb[pi], ya[ti][pi], 0, 0, 0);
                ua[ti][pi] = __builtin_amdgcn_mfma_f32_16x16x32_bf16(cf[ti][kh], hb2[pi], ua[ti][pi], 0, 0, 0);
            }
        }
    }
    unsigned short* yrow = ybb + tok0 * DI + h * HD;
    #pragma unroll
    for (int ti = 0; ti < 4; ti++)
        #pragma unroll
        for (int pi = 0; pi < 2; pi++)
            #pragma unroll
            for (int r = 0; r < 4; r++) {
                int t = ti * 16 + ko * 4 + r;
                yrow[(size_t)t * DI + pi * 16 + m] =
                    f2bfbits(ya[ti][pi][r] + et[ti][r] * ua[ti][pi][r]);
            }
}

// ---------------- 6+7. fused gate + GEMM2 + residual (no LDS, frag-packed W2) --
__global__ __launch_bounds__(256, 4) void k_gemm2g(const unsigned short* __restrict__ ybb,
                                                   const unsigned short* __restrict__ zb,
                                                   const unsigned short* __restrict__ w2f,
                                                   const float* __restrict__ xin,
                                                   float* __restrict__ out) {
    const int t = threadIdx.x;
    const int wave = t >> 6, lane = t & 63;
    const int fr = lane & 15, ko = lane >> 4;
    const int m0 = blockIdx.x * 64 + wave * 16;
    const size_t rowo = (size_t)(m0 + fr) * DI;
    float ss = 0.f;
    bf16x8 gb[8];
    #pragma unroll
    for (int kk = 0; kk < 8; kk++) {
        int co = kk * 32 + ko * 8;
        bf16x8 yv = *(const bf16x8*)(ybb + rowo + co);
        bf16x8 zv = *(const bf16x8*)(zb + rowo + co);
        #pragma unroll
        for (int j = 0; j < 8; j++) {
            float z = (float)zv[j];
            float g = (float)yv[j] * (z / (1.f + expf(-z)));
            ss += g * g;
            gb[kk][j] = (bf16)g;
        }
    }
    ss += __shfl_xor(ss, 16);
    ss += __shfl_xor(ss, 32);
    const float rs = rsqrtf(ss * (1.0f / DI) + EPSF);
    #pragma unroll
    for (int kk = 0; kk < 8; kk++)
        #pragma unroll
        for (int j = 0; j < 8; j++)
            gb[kk][j] = (bf16)((float)gb[kk][j] * rs);
    const unsigned short* wp = w2f + (size_t)lane * 8;
    f32x4 acc[8] = {};
    #pragma unroll
    for (int kk = 0; kk < 8; kk++) {
        #pragma unroll
        for (int nt = 0; nt < 8; nt++) {
            bf16x8 bfr = *(const bf16x8*)(wp + (((size_t)kk * 8 + nt) << 9));
            acc[nt] = __builtin_amdgcn_mfma_f32_16x16x32_bf16(gb[kk], bfr, acc[nt], 0, 0, 0);
        }
    }
    #pragma unroll
    for (int nt = 0; nt < 8; nt++) {
        int n = nt * 16 + fr;
        #pragma unroll
        for (int rr = 0; rr < 4; rr++) {
            int m = m0 + ko * 4 + rr;
            out[(size_t)m * DM + n] = xin[(size_t)m * DM + n] + acc[nt][rr];
        }
    }
}

extern "C" void kernel_launch(void* const* d_in, const int* in_sizes, int n_in,
                              void* d_out, int out_size, void* d_ws, size_t ws_size,
                              hipStream_t stream) {
    const float* x   = (const float*)d_in[0];
    const float* nw  = (const float*)d_in[1];
    const float* w1  = (const float*)d_in[2];
    const float* cw  = (const float*)d_in[3];
    const float* cb  = (const float*)d_in[4];
    const float* dtb = (const float*)d_in[5];
    const float* al  = (const float*)d_in[6];
    const float* Dw  = (const float*)d_in[7];
    const float* gw  = (const float*)d_in[8];
    const float* w2  = (const float*)d_in[9];
    float* out = (float*)d_out;

    float* ws = (float*)d_ws;
    float*  dAp = ws;                                   // 4096 fp32
    float*  dtf = dAp + NB * NH * NC;                   // NTOK*8 fp32
    unsigned short* hst = (unsigned short*)(dtf + (size_t)NTOK * NH); // 64*64*2048 bf16
    unsigned short* zb  = hst + (size_t)NB * NH * NC * 2048;          // NTOK*256
    unsigned short* xbc = zb + (size_t)NTOK * DI;                     // NTOK*384 (pre-conv)
    unsigned short* bcA = xbc + (size_t)NTOK * CDIM;                  // NTOK*128 (B|C tok-major)
    unsigned short* xT  = bcA + (size_t)NTOK * 128;                   // 256*NTOK (x ch-major)
    unsigned short* bT  = xT + (size_t)DI * NTOK;                     // 64*NTOK  (B ch-major)
    unsigned short* ybb = bT + (size_t)64 * NTOK;                     // NTOK*256
    unsigned short* w1g = ybb + (size_t)NTOK * DI;                    // 640*128 frag-packed
    unsigned short* w2f = w1g + (size_t)640 * DM;                     // 128*256 frag-packed

    k_prep<<<(640 * DM + DM * DI + 255) / 256, 256, 0, stream>>>(w1, w2, gw, w1g, w2f);
    k_gemm1<<<NTOK / 64, 256, 0, stream>>>(x, nw, w1, dtb, w1g, zb, xbc, dtf);
    k_conv<<<NTOK / 64, 384, 0, stream>>>(xbc, cw, cb, bcA, xT, bT);
    k_ssd1<<<NB * NH * (NC / 4), 256, 0, stream>>>(bT, xT, dtf, al, hst, dAp);
    k_ssm2<<<NB * NH * 8, 256, 0, stream>>>(hst, dAp);
    k_ssd3<<<NB * NH * (NC / 4), 256, 0, stream>>>(bcA, xT, dtf, al, hst, Dw, ybb);
    k_gemm2g<<<NTOK / 64, 256, 0, stream>>>(ybb, zb, w2f, x, out);
}

// Round 5
// 189.079 us; speedup vs baseline: 1.0780x; 1.0273x over previous
//
#include <hip/hip_runtime.h>

#define DM    128
#define DI    256
#define NH    8
#define HD    32
#define NS    64
#define CDIM  384
#define DPROJ 648
#define LSEQ  4096
#define NB    8
#define NTOK  32768          // NB*LSEQ
#define LC    64             // chunk length
#define NC    64             // chunks per (b,h) sequence
#define EPSF  1e-5f
#define LOG2E 1.4426950408889634f

typedef __bf16 bf16;
typedef bf16  bf16x8 __attribute__((ext_vector_type(8)));
typedef bf16  bf16x4 __attribute__((ext_vector_type(4)));
typedef short short8 __attribute__((ext_vector_type(8)));
typedef float f32x4  __attribute__((ext_vector_type(4)));

__device__ __forceinline__ unsigned short f2bfbits(float f) {
    unsigned int u = __float_as_uint(f);
    unsigned int r = u + 0x7FFFu + ((u >> 16) & 1u);   // RNE
    return (unsigned short)(r >> 16);
}
__device__ __forceinline__ float bfbits2f(unsigned short u) {
    return __uint_as_float(((unsigned int)u) << 16);
}

// ---------------- 0. prep: W1 + W2 fragment-packs (gnorm folded into W2) -------
__global__ __launch_bounds__(256) void k_prep(const float* __restrict__ w1,
                                              const float* __restrict__ w2,
                                              const float* __restrict__ gw,
                                              unsigned short* __restrict__ w1g,
                                              unsigned short* __restrict__ w2f) {
    int i = blockIdx.x * 256 + threadIdx.x;
    if (i < 640 * DM) {
        int f = i >> 9, r = i & 511;
        int lane = r >> 3, jj = r & 7;
        int ns = f >> 2, kk = f & 3;
        int n = ns * 16 + (lane & 15), k = kk * 32 + (lane >> 4) * 8 + jj;
        w1g[i] = f2bfbits(w1[(size_t)n * DM + k]);
    } else {
        int j = i - 640 * DM;
        if (j < DM * DI) {
            int f = j >> 9, r = j & 511;
            int lane = r >> 3, jj = r & 7;
            int kk = f >> 3, nt = f & 7;
            int fr = lane & 15, ko = lane >> 4;
            int n = nt * 16 + fr, k = kk * 32 + ko * 8 + jj;
            w2f[j] = f2bfbits(w2[(size_t)n * DI + k] * gw[k]);
        }
    }
}

// ---------------- 1+2. fused RMSNorm + dt + GEMM1, grid.y=2 over n-tiles -------
// y==0 handles n-tiles 0..4 (z | xBC start) + dt; y==1 handles 5..9.
// Phase-1 rmsnorm duplicated across y (x is L3-hot); 4 blocks/CU occupancy.
__global__ __launch_bounds__(256, 4) void k_gemm1(const float* __restrict__ x,
                                                  const float* __restrict__ nw,
                                                  const float* __restrict__ w1,
                                                  const float* __restrict__ dtb,
                                                  const unsigned short* __restrict__ w1g,
                                                  unsigned short* __restrict__ zb,
                                                  unsigned short* __restrict__ xbc,
                                                  float* __restrict__ dtf) {
    __shared__ float Xs[64][132];
    __shared__ float Wd[8][132];
    const int t = threadIdx.x;
    const int wave = t >> 6, lane = t & 63;
    const int m0 = blockIdx.x * 64;
    const int ny = blockIdx.y;
    if (ny == 0) {   // stage dt weight rows (w1[640..647]) once
        int row = t >> 5, col = (t & 31) * 4;
        *(float4*)&Wd[row][col] = *(const float4*)(w1 + (size_t)(640 + row) * DM + col);
    }
    // phase 1: rmsnorm 16 rows per wave -> fp32 LDS
    const float nw0 = nw[lane * 2], nw1 = nw[lane * 2 + 1];
    #pragma unroll
    for (int i = 0; i < 16; i++) {
        int r = wave * 16 + i;
        const float* xr = x + (size_t)(m0 + r) * DM + lane * 2;
        float v0 = xr[0], v1 = xr[1];
        float ss = v0 * v0 + v1 * v1;
        #pragma unroll
        for (int o = 32; o; o >>= 1) ss += __shfl_xor(ss, o);
        float rs = rsqrtf(ss * (1.0f / DM) + EPSF);
        Xs[r][lane * 2]     = v0 * rs * nw0;
        Xs[r][lane * 2 + 1] = v1 * rs * nw1;
    }
    __syncthreads();
    // phase 2a: dt (fp32 exact), only y==0
    if (ny == 0) {
        const int h = lane >> 3, ks = lane & 7;
        const float dtbh = dtb[h];
        #pragma unroll
        for (int i = 0; i < 16; i++) {
            int r = wave * 16 + i;
            float acc = 0.f;
            #pragma unroll
            for (int q = 0; q < 4; q++) {
                float4 xv = *(const float4*)&Xs[r][ks * 16 + q * 4];
                float4 wv = *(const float4*)&Wd[h][ks * 16 + q * 4];
                acc = fmaf(xv.x, wv.x, acc); acc = fmaf(xv.y, wv.y, acc);
                acc = fmaf(xv.z, wv.z, acc); acc = fmaf(xv.w, wv.w, acc);
            }
            acc += __shfl_xor(acc, 1);
            acc += __shfl_xor(acc, 2);
            acc += __shfl_xor(acc, 4);
            if (ks == 0) {
                float v = acc + dtbh;
                dtf[(size_t)(m0 + r) * NH + h] = (v > 20.f) ? v : log1pf(expf(v));
            }
        }
    }
    // phase 2b: bf16 A-frags from Xs
    const int wm = wave >> 1, wn = wave & 1;
    const int fr = lane & 15, ko = lane >> 4;
    bf16x8 a[2][4];
    #pragma unroll
    for (int mt = 0; mt < 2; mt++)
        #pragma unroll
        for (int kk = 0; kk < 4; kk++) {
            const float* src = &Xs[wm * 32 + mt * 16 + fr][kk * 32 + ko * 8];
            float4 lo = *(const float4*)src, hi = *(const float4*)(src + 4);
            bf16x8 af;
            af[0] = (bf16)lo.x; af[1] = (bf16)lo.y; af[2] = (bf16)lo.z; af[3] = (bf16)lo.w;
            af[4] = (bf16)hi.x; af[5] = (bf16)hi.y; af[6] = (bf16)hi.z; af[7] = (bf16)hi.w;
            a[mt][kk] = af;
        }
    // n-tile loop: 5 x 64 cols per y-slice, B-frags = coalesced 1KB wave loads
    for (int i = 0; i < 5; i++) {
        int nt = ny * 5 + i;
        const unsigned short* wb = w1g + (((size_t)(nt * 4 + wn * 2) * 4) << 9) + lane * 8;
        f32x4 acc[2][2] = {};
        #pragma unroll
        for (int kk = 0; kk < 4; kk++) {
            bf16x8 b0 = *(const bf16x8*)(wb + ((size_t)kk << 9));
            bf16x8 b1 = *(const bf16x8*)(wb + ((size_t)(4 + kk) << 9));
            acc[0][0] = __builtin_amdgcn_mfma_f32_16x16x32_bf16(a[0][kk], b0, acc[0][0], 0, 0, 0);
            acc[1][0] = __builtin_amdgcn_mfma_f32_16x16x32_bf16(a[1][kk], b0, acc[1][0], 0, 0, 0);
            acc[0][1] = __builtin_amdgcn_mfma_f32_16x16x32_bf16(a[0][kk], b1, acc[0][1], 0, 0, 0);
            acc[1][1] = __builtin_amdgcn_mfma_f32_16x16x32_bf16(a[1][kk], b1, acc[1][1], 0, 0, 0);
        }
        unsigned short* dst; int ld, nc0;
        if (nt < 4) { dst = zb;  ld = DI;   nc0 = nt * 64; }
        else        { dst = xbc; ld = CDIM; nc0 = nt * 64 - 256; }
        #pragma unroll
        for (int mt = 0; mt < 2; mt++)
            #pragma unroll
            for (int ntt = 0; ntt < 2; ntt++) {
                int n = nc0 + wn * 32 + ntt * 16 + fr;
                #pragma unroll
                for (int rr = 0; rr < 4; rr++) {
                    int m = m0 + wm * 32 + mt * 16 + ko * 4 + rr;
                    dst[(size_t)m * ld + n] = f2bfbits(acc[mt][ntt][rr]);
                }
            }
    }
}

// ---------------- 3+5a. fused conv + SSD pass 1 --------------------------------
// Block = one 64-token chunk, 512 threads. Phase A (threads<384): causal conv
// K=4 + SiLU into LDS [ch][tok] (+ bcA token-major for B|C). Phase B: xT
// writeout (x channels, for ssd3). Phase C: wave h computes head h's
// chunk-local end state (identical math to old k_ssd1, frags from LDS).
__global__ __launch_bounds__(512) void k_conv1(const unsigned short* __restrict__ xbc,
                                               const float* __restrict__ cw,
                                               const float* __restrict__ cb,
                                               const float* __restrict__ dtf,
                                               const float* __restrict__ alog,
                                               unsigned short* __restrict__ bcA,
                                               unsigned short* __restrict__ xT,
                                               unsigned short* __restrict__ hst,
                                               float* __restrict__ dAp) {
    __shared__ __align__(16) unsigned short L[320][72];
    __shared__ float wlh[NH][64];
    const int tid = threadIdx.x;
    const int t0 = blockIdx.x * 64;
    // --- phase A: conv (channels 0..383) ---
    if (tid < CDIM) {
        const int ch = tid;
        const int l0 = t0 & (LSEQ - 1);
        float4 wv = *(const float4*)(cw + ch * 4);
        float bias = cb[ch];
        const unsigned short* in = xbc + (size_t)t0 * CDIM + ch;
        float h1 = 0.f, h2 = 0.f, h3 = 0.f;
        if (l0) {
            h1 = bfbits2f(in[-CDIM]);
            h2 = bfbits2f(in[-2 * CDIM]);
            h3 = bfbits2f(in[-3 * CDIM]);
        }
        short8 pk;
        #pragma unroll 8
        for (int t = 0; t < 64; t++) {
            float x0 = bfbits2f(in[(size_t)t * CDIM]);
            float acc = bias;
            acc = fmaf(x0, wv.w, acc);
            acc = fmaf(h1, wv.z, acc);
            acc = fmaf(h2, wv.y, acc);
            acc = fmaf(h3, wv.x, acc);
            float s = acc / (1.f + expf(-acc));
            unsigned short us = f2bfbits(s);
            if (ch >= 256) bcA[(size_t)(t0 + t) * 128 + (ch - 256)] = us;  // B|C tok-major
            pk[t & 7] = (short)us;
            if (ch < 320 && (t & 7) == 7) *(short8*)&L[ch][t - 7] = pk;
            h3 = h2; h2 = h1; h1 = x0;
        }
    }
    __syncthreads();
    // --- phase B: xT writeout (256 x-channel rows x 8 token-chunks) ---
    {
        int idx = tid;
        #pragma unroll
        for (int it = 0; it < 4; it++, idx += 512) {
            int row = idx >> 3, tc = (idx & 7) * 8;
            *(short8*)(xT + (size_t)row * NTOK + t0 + tc) = *(const short8*)&L[row][tc];
        }
    }
    // --- phase C: chunk-local end state, wave = head ---
    const int h = tid >> 6, lane = tid & 63;
    const int b = blockIdx.x >> 6, c = blockIdx.x & 63;
    const int bh = b * NH + h;
    const float A = -expf(alog[h]);
    float dt = dtf[(size_t)(t0 + lane) * NH + h];
    float q = dt * A * LOG2E;
    #pragma unroll
    for (int o = 1; o <= 32; o <<= 1) {
        float tmp = __shfl_up(q, o);
        if (lane >= o) q += tmp;
    }
    float qL = __shfl(q, 63);
    wlh[h][lane] = exp2f(qL - q) * dt;        // intra-wave LDS: no barrier needed
    if (lane == 0) dAp[(size_t)bh * NC + c] = exp2f(qL);
    const int m = lane & 15, ko = lane >> 4;
    f32x4 hacc[4][2] = {};
    #pragma unroll
    for (int kh = 0; kh < 2; kh++) {
        bf16x8 xb[2];
        #pragma unroll
        for (int pi = 0; pi < 2; pi++)
            xb[pi] = *(const bf16x8*)&L[h * HD + pi * 16 + m][kh * 32 + ko * 8];
        f32x4 w0 = *(const f32x4*)&wlh[h][kh * 32 + ko * 8];
        f32x4 w1v = *(const f32x4*)&wlh[h][kh * 32 + ko * 8 + 4];
        #pragma unroll
        for (int ni = 0; ni < 4; ni++) {
            bf16x8 bv = *(const bf16x8*)&L[256 + ni * 16 + m][kh * 32 + ko * 8];
            bf16x8 af;
            #pragma unroll
            for (int j = 0; j < 4; j++) af[j] = (bf16)((float)bv[j] * w0[j]);
            #pragma unroll
            for (int j = 0; j < 4; j++) af[4 + j] = (bf16)((float)bv[4 + j] * w1v[j]);
            #pragma unroll
            for (int pi = 0; pi < 2; pi++)
                hacc[ni][pi] = __builtin_amdgcn_mfma_f32_16x16x32_bf16(af, xb[pi], hacc[ni][pi], 0, 0, 0);
        }
    }
    unsigned short* hb = hst + (((size_t)bh * NC + c) << 11);
    #pragma unroll
    for (int ni = 0; ni < 4; ni++)
        #pragma unroll
        for (int pi = 0; pi < 2; pi++) {
            bf16x4 pv;
            #pragma unroll
            for (int r = 0; r < 4; r++) pv[r] = (bf16)hacc[ni][pi][r];
            *(bf16x4*)(hb + (pi * 16 + m) * 64 + ni * 16 + ko * 4) = pv;
        }
}

// ---------------- 5b. SSM pass 2: scan, 1 bh/block, depth-4 load pipeline ------
__global__ __launch_bounds__(256) void k_ssm2(unsigned short* __restrict__ hst,
                                              const float* __restrict__ dAp) {
    __shared__ float dl[NC];
    const int bh = blockIdx.x >> 3, seg = blockIdx.x & 7;
    const int s = seg * 256 + threadIdx.x;
    if (threadIdx.x < NC) dl[threadIdx.x] = dAp[(size_t)bh * NC + threadIdx.x];
    __syncthreads();
    unsigned short* p = hst + ((size_t)bh * NC << 11) + s;
    float r = 0.f;
    float v0 = bfbits2f(p[0]);
    float v1 = bfbits2f(p[(size_t)1 << 11]);
    float v2 = bfbits2f(p[(size_t)2 << 11]);
    float v3 = bfbits2f(p[(size_t)3 << 11]);
    for (int c = 0; c < NC; c += 4) {
        float t;
        t = v0; if (c + 4 < NC) v0 = bfbits2f(p[(size_t)(c + 4) << 11]);
        p[(size_t)c << 11] = f2bfbits(r);       r = fmaf(r, dl[c], t);
        t = v1; if (c + 5 < NC) v1 = bfbits2f(p[(size_t)(c + 5) << 11]);
        p[(size_t)(c + 1) << 11] = f2bfbits(r); r = fmaf(r, dl[c + 1], t);
        t = v2; if (c + 6 < NC) v2 = bfbits2f(p[(size_t)(c + 6) << 11]);
        p[(size_t)(c + 2) << 11] = f2bfbits(r); r = fmaf(r, dl[c + 2], t);
        t = v3; if (c + 7 < NC) v3 = bfbits2f(p[(size_t)(c + 7) << 11]);
        p[(size_t)(c + 3) << 11] = f2bfbits(r); r = fmaf(r, dl[c + 3], t);
    }
}

// ---------------- 5c. SSD pass 3: Y = P.X + diag(2^q).(C.h_in^T) ---------------
__global__ __launch_bounds__(256, 2) void k_ssd3(const unsigned short* __restrict__ bcA,
                                                 const unsigned short* __restrict__ xT,
                                                 const float* __restrict__ dtf,
                                                 const float* __restrict__ alog,
                                                 const unsigned short* __restrict__ hst,
                                                 const float* __restrict__ Dw,
                                                 unsigned short* __restrict__ ybb) {
    __shared__ __align__(16) bf16 Pl[4][64 * 72];
    __shared__ __align__(16) float ql[4][64];
    __shared__ __align__(16) float dl[4][64];
    const int bh = blockIdx.x >> 4, cg = blockIdx.x & 15;
    const int b = bh >> 3, h = bh & 7;
    const int wave = threadIdx.x >> 6, lane = threadIdx.x & 63;
    const int c = cg * 4 + wave;
    const size_t tok0 = (size_t)b * LSEQ + c * LC;
    const float A = -expf(alog[h]);
    const float Dh = Dw[h];
    float dt = dtf[(tok0 + lane) * NH + h];
    float q = dt * A * LOG2E;
    #pragma unroll
    for (int o = 1; o <= 32; o <<= 1) {
        float tmp = __shfl_up(q, o);
        if (lane >= o) q += tmp;
    }
    ql[wave][lane] = q;
    dl[wave][lane] = dt;
    const int m = lane & 15, ko = lane >> 4;
    bf16x8 cf[4][2];
    #pragma unroll
    for (int ti = 0; ti < 4; ti++)
        #pragma unroll
        for (int kh = 0; kh < 2; kh++)
            cf[ti][kh] = *(const bf16x8*)(bcA + (tok0 + ti * 16 + m) * 128 + 64 + kh * 32 + ko * 8);
    f32x4 gt[4][4] = {};
    #pragma unroll
    for (int kh = 0; kh < 2; kh++) {
        bf16x8 bfg[4];
        #pragma unroll
        for (int si = 0; si < 4; si++)
            bfg[si] = *(const bf16x8*)(bcA + (tok0 + si * 16 + m) * 128 + kh * 32 + ko * 8);
        #pragma unroll
        for (int ti = 0; ti < 4; ti++)
            #pragma unroll
            for (int si = 0; si < 4; si++)
                gt[ti][si] = __builtin_amdgcn_mfma_f32_16x16x32_bf16(bfg[si], cf[ti][kh], gt[ti][si], 0, 0, 0);
    }
    float qt[4];
    #pragma unroll
    for (int ti = 0; ti < 4; ti++) qt[ti] = ql[wave][ti * 16 + m];
    #pragma unroll
    for (int si = 0; si < 4; si++) {
        f32x4 qs = *(const f32x4*)&ql[wave][si * 16 + ko * 4];
        f32x4 ds = *(const f32x4*)&dl[wave][si * 16 + ko * 4];
        #pragma unroll
        for (int ti = 0; ti < 4; ti++) {
            bf16x4 pv = {};
            if (si <= ti) {
                const int t = ti * 16 + m;
                #pragma unroll
                for (int r = 0; r < 4; r++) {
                    int s = si * 16 + ko * 4 + r;
                    float p = 0.f;
                    if (s <= t) {
                        p = exp2f(qt[ti] - qs[r]) * ds[r] * gt[ti][si][r];
                        if (s == t) p += Dh;
                    }
                    pv[r] = (bf16)p;
                }
            }
            *(bf16x4*)&Pl[wave][(ti * 16 + m) * 72 + si * 16 + ko * 4] = pv;
        }
    }
    f32x4 et[4];
    #pragma unroll
    for (int ti = 0; ti < 4; ti++) {
        f32x4 qv = *(const f32x4*)&ql[wave][ti * 16 + ko * 4];
        #pragma unroll
        for (int r = 0; r < 4; r++) et[ti][r] = exp2f(qv[r]);
    }
    const size_t hbase = ((size_t)bh * NC + c) << 11;
    f32x4 ya[4][2] = {}, ua[4][2] = {};
    #pragma unroll
    for (int kh = 0; kh < 2; kh++) {
        bf16x8 xb[2], hb2[2];
        #pragma unroll
        for (int pi = 0; pi < 2; pi++) {
            xb[pi]  = *(const bf16x8*)(xT + (size_t)(h * HD + pi * 16 + m) * NTOK + tok0 + kh * 32 + ko * 8);
            hb2[pi] = *(const bf16x8*)(hst + hbase + (pi * 16 + m) * 64 + kh * 32 + ko * 8);
        }
        #pragma unroll
        for (int ti = 0; ti < 4; ti++) {
            bf16x8 pa = *(const bf16x8*)&Pl[wave][(ti * 16 + m) * 72 + kh * 32 + ko * 8];
            #pragma unroll
            for (int pi = 0; pi < 2; pi++) {
                ya[ti][pi] = __builtin_amdgcn_mfma_f32_16x16x32_bf16(pa, xb[pi], ya[ti][pi], 0, 0, 0);
                ua[ti][pi] = __builtin_amdgcn_mfma_f32_16x16x32_bf16(cf[ti][kh], hb2[pi], ua[ti][pi], 0, 0, 0);
            }
        }
    }
    unsigned short* yrow = ybb + tok0 * DI + h * HD;
    #pragma unroll
    for (int ti = 0; ti < 4; ti++)
        #pragma unroll
        for (int pi = 0; pi < 2; pi++)
            #pragma unroll
            for (int r = 0; r < 4; r++) {
                int t = ti * 16 + ko * 4 + r;
                yrow[(size_t)t * DI + pi * 16 + m] =
                    f2bfbits(ya[ti][pi][r] + et[ti][r] * ua[ti][pi][r]);
            }
}

// ---------------- 6+7. fused gate + GEMM2 + residual (no LDS, frag-packed W2) --
__global__ __launch_bounds__(256, 4) void k_gemm2g(const unsigned short* __restrict__ ybb,
                                                   const unsigned short* __restrict__ zb,
                                                   const unsigned short* __restrict__ w2f,
                                                   const float* __restrict__ xin,
                                                   float* __restrict__ out) {
    const int t = threadIdx.x;
    const int wave = t >> 6, lane = t & 63;
    const int fr = lane & 15, ko = lane >> 4;
    const int m0 = blockIdx.x * 64 + wave * 16;
    const size_t rowo = (size_t)(m0 + fr) * DI;
    float ss = 0.f;
    bf16x8 gb[8];
    #pragma unroll
    for (int kk = 0; kk < 8; kk++) {
        int co = kk * 32 + ko * 8;
        bf16x8 yv = *(const bf16x8*)(ybb + rowo + co);
        bf16x8 zv = *(const bf16x8*)(zb + rowo + co);
        #pragma unroll
        for (int j = 0; j < 8; j++) {
            float z = (float)zv[j];
            float g = (float)yv[j] * (z / (1.f + expf(-z)));
            ss += g * g;
            gb[kk][j] = (bf16)g;
        }
    }
    ss += __shfl_xor(ss, 16);
    ss += __shfl_xor(ss, 32);
    const float rs = rsqrtf(ss * (1.0f / DI) + EPSF);
    #pragma unroll
    for (int kk = 0; kk < 8; kk++)
        #pragma unroll
        for (int j = 0; j < 8; j++)
            gb[kk][j] = (bf16)((float)gb[kk][j] * rs);
    const unsigned short* wp = w2f + (size_t)lane * 8;
    f32x4 acc[8] = {};
    #pragma unroll
    for (int kk = 0; kk < 8; kk++) {
        #pragma unroll
        for (int nt = 0; nt < 8; nt++) {
            bf16x8 bfr = *(const bf16x8*)(wp + (((size_t)kk * 8 + nt) << 9));
            acc[nt] = __builtin_amdgcn_mfma_f32_16x16x32_bf16(gb[kk], bfr, acc[nt], 0, 0, 0);
        }
    }
    #pragma unroll
    for (int nt = 0; nt < 8; nt++) {
        int n = nt * 16 + fr;
        #pragma unroll
        for (int rr = 0; rr < 4; rr++) {
            int m = m0 + ko * 4 + rr;
            out[(size_t)m * DM + n] = xin[(size_t)m * DM + n] + acc[nt][rr];
        }
    }
}

extern "C" void kernel_launch(void* const* d_in, const int* in_sizes, int n_in,
                              void* d_out, int out_size, void* d_ws, size_t ws_size,
                              hipStream_t stream) {
    const float* x   = (const float*)d_in[0];
    const float* nw  = (const float*)d_in[1];
    const float* w1  = (const float*)d_in[2];
    const float* cw  = (const float*)d_in[3];
    const float* cb  = (const float*)d_in[4];
    const float* dtb = (const float*)d_in[5];
    const float* al  = (const float*)d_in[6];
    const float* Dw  = (const float*)d_in[7];
    const float* gw  = (const float*)d_in[8];
    const float* w2  = (const float*)d_in[9];
    float* out = (float*)d_out;

    float* ws = (float*)d_ws;
    float*  dAp = ws;                                   // 4096 fp32
    float*  dtf = dAp + NB * NH * NC;                   // NTOK*8 fp32
    unsigned short* hst = (unsigned short*)(dtf + (size_t)NTOK * NH); // 64*64*2048 bf16
    unsigned short* zb  = hst + (size_t)NB * NH * NC * 2048;          // NTOK*256
    unsigned short* xbc = zb + (size_t)NTOK * DI;                     // NTOK*384 (pre-conv)
    unsigned short* bcA = xbc + (size_t)NTOK * CDIM;                  // NTOK*128 (B|C tok-major)
    unsigned short* xT  = bcA + (size_t)NTOK * 128;                   // 256*NTOK (x ch-major)
    unsigned short* ybb = xT + (size_t)DI * NTOK;                     // NTOK*256
    unsigned short* w1g = ybb + (size_t)NTOK * DI;                    // 640*128 frag-packed
    unsigned short* w2f = w1g + (size_t)640 * DM;                     // 128*256 frag-packed

    k_prep<<<(640 * DM + DM * DI + 255) / 256, 256, 0, stream>>>(w1, w2, gw, w1g, w2f);
    k_gemm1<<<dim3(NTOK / 64, 2), 256, 0, stream>>>(x, nw, w1, dtb, w1g, zb, xbc, dtf);
    k_conv1<<<NTOK / 64, 512, 0, stream>>>(xbc, cw, cb, dtf, al, bcA, xT, hst, dAp);
    k_ssm2<<<NB * NH * 8, 256, 0, stream>>>(hst, dAp);
    k_ssd3<<<NB * NH * (NC / 4), 256, 0, stream>>>(bcA, xT, dtf, al, hst, Dw, ybb);
    k_gemm2g<<<NTOK / 64, 256, 0, stream>>>(ybb, zb, w2f, x, out);
}

// Round 6
// 177.019 us; speedup vs baseline: 1.1514x; 1.0681x over previous
//
#include <hip/hip_runtime.h>

#define DM    128
#define DI    256
#define NH    8
#define HD    32
#define NS    64
#define CDIM  384
#define DPROJ 648
#define LSEQ  4096
#define NB    8
#define NTOK  32768          // NB*LSEQ
#define LC    64             // chunk length
#define NC    64             // chunks per (b,h) sequence
#define EPSF  1e-5f
#define LOG2E 1.4426950408889634f

typedef __bf16 bf16;
typedef bf16  bf16x8 __attribute__((ext_vector_type(8)));
typedef bf16  bf16x4 __attribute__((ext_vector_type(4)));
typedef short short8 __attribute__((ext_vector_type(8)));
typedef float f32x4  __attribute__((ext_vector_type(4)));

__device__ __forceinline__ unsigned short f2bfbits(float f) {
    unsigned int u = __float_as_uint(f);
    unsigned int r = u + 0x7FFFu + ((u >> 16) & 1u);   // RNE
    return (unsigned short)(r >> 16);
}
__device__ __forceinline__ float bfbits2f(unsigned short u) {
    return __uint_as_float(((unsigned int)u) << 16);
}

// ---------------- 0. prep: W1 + W2 fragment-packs (gnorm folded into W2) -------
__global__ __launch_bounds__(256) void k_prep(const float* __restrict__ w1,
                                              const float* __restrict__ w2,
                                              const float* __restrict__ gw,
                                              unsigned short* __restrict__ w1g,
                                              unsigned short* __restrict__ w2f) {
    int i = blockIdx.x * 256 + threadIdx.x;
    if (i < 640 * DM) {
        int f = i >> 9, r = i & 511;
        int lane = r >> 3, jj = r & 7;
        int ns = f >> 2, kk = f & 3;
        int n = ns * 16 + (lane & 15), k = kk * 32 + (lane >> 4) * 8 + jj;
        w1g[i] = f2bfbits(w1[(size_t)n * DM + k]);
    } else {
        int j = i - 640 * DM;
        if (j < DM * DI) {
            int f = j >> 9, r = j & 511;
            int lane = r >> 3, jj = r & 7;
            int kk = f >> 3, nt = f & 7;
            int fr = lane & 15, ko = lane >> 4;
            int n = nt * 16 + fr, k = kk * 32 + ko * 8 + jj;
            w2f[j] = f2bfbits(w2[(size_t)n * DI + k] * gw[k]);
        }
    }
}

// ---------------- 1+2. fused RMSNorm + dt + GEMM1, grid.y=2 over n-tiles -------
__global__ __launch_bounds__(256, 4) void k_gemm1(const float* __restrict__ x,
                                                  const float* __restrict__ nw,
                                                  const float* __restrict__ w1,
                                                  const float* __restrict__ dtb,
                                                  const unsigned short* __restrict__ w1g,
                                                  unsigned short* __restrict__ zb,
                                                  unsigned short* __restrict__ xbc,
                                                  float* __restrict__ dtf) {
    __shared__ float Xs[64][132];
    __shared__ float Wd[8][132];
    const int t = threadIdx.x;
    const int wave = t >> 6, lane = t & 63;
    const int m0 = blockIdx.x * 64;
    const int ny = blockIdx.y;
    if (ny == 0) {   // stage dt weight rows (w1[640..647]) once
        int row = t >> 5, col = (t & 31) * 4;
        *(float4*)&Wd[row][col] = *(const float4*)(w1 + (size_t)(640 + row) * DM + col);
    }
    const float nw0 = nw[lane * 2], nw1 = nw[lane * 2 + 1];
    #pragma unroll
    for (int i = 0; i < 16; i++) {
        int r = wave * 16 + i;
        const float* xr = x + (size_t)(m0 + r) * DM + lane * 2;
        float v0 = xr[0], v1 = xr[1];
        float ss = v0 * v0 + v1 * v1;
        #pragma unroll
        for (int o = 32; o; o >>= 1) ss += __shfl_xor(ss, o);
        float rs = rsqrtf(ss * (1.0f / DM) + EPSF);
        Xs[r][lane * 2]     = v0 * rs * nw0;
        Xs[r][lane * 2 + 1] = v1 * rs * nw1;
    }
    __syncthreads();
    if (ny == 0) {
        const int h = lane >> 3, ks = lane & 7;
        const float dtbh = dtb[h];
        #pragma unroll
        for (int i = 0; i < 16; i++) {
            int r = wave * 16 + i;
            float acc = 0.f;
            #pragma unroll
            for (int q = 0; q < 4; q++) {
                float4 xv = *(const float4*)&Xs[r][ks * 16 + q * 4];
                float4 wv = *(const float4*)&Wd[h][ks * 16 + q * 4];
                acc = fmaf(xv.x, wv.x, acc); acc = fmaf(xv.y, wv.y, acc);
                acc = fmaf(xv.z, wv.z, acc); acc = fmaf(xv.w, wv.w, acc);
            }
            acc += __shfl_xor(acc, 1);
            acc += __shfl_xor(acc, 2);
            acc += __shfl_xor(acc, 4);
            if (ks == 0) {
                float v = acc + dtbh;
                dtf[(size_t)(m0 + r) * NH + h] = (v > 20.f) ? v : log1pf(expf(v));
            }
        }
    }
    const int wm = wave >> 1, wn = wave & 1;
    const int fr = lane & 15, ko = lane >> 4;
    bf16x8 a[2][4];
    #pragma unroll
    for (int mt = 0; mt < 2; mt++)
        #pragma unroll
        for (int kk = 0; kk < 4; kk++) {
            const float* src = &Xs[wm * 32 + mt * 16 + fr][kk * 32 + ko * 8];
            float4 lo = *(const float4*)src, hi = *(const float4*)(src + 4);
            bf16x8 af;
            af[0] = (bf16)lo.x; af[1] = (bf16)lo.y; af[2] = (bf16)lo.z; af[3] = (bf16)lo.w;
            af[4] = (bf16)hi.x; af[5] = (bf16)hi.y; af[6] = (bf16)hi.z; af[7] = (bf16)hi.w;
            a[mt][kk] = af;
        }
    for (int i = 0; i < 5; i++) {
        int nt = ny * 5 + i;
        const unsigned short* wb = w1g + (((size_t)(nt * 4 + wn * 2) * 4) << 9) + lane * 8;
        f32x4 acc[2][2] = {};
        #pragma unroll
        for (int kk = 0; kk < 4; kk++) {
            bf16x8 b0 = *(const bf16x8*)(wb + ((size_t)kk << 9));
            bf16x8 b1 = *(const bf16x8*)(wb + ((size_t)(4 + kk) << 9));
            acc[0][0] = __builtin_amdgcn_mfma_f32_16x16x32_bf16(a[0][kk], b0, acc[0][0], 0, 0, 0);
            acc[1][0] = __builtin_amdgcn_mfma_f32_16x16x32_bf16(a[1][kk], b0, acc[1][0], 0, 0, 0);
            acc[0][1] = __builtin_amdgcn_mfma_f32_16x16x32_bf16(a[0][kk], b1, acc[0][1], 0, 0, 0);
            acc[1][1] = __builtin_amdgcn_mfma_f32_16x16x32_bf16(a[1][kk], b1, acc[1][1], 0, 0, 0);
        }
        unsigned short* dst; int ld, nc0;
        if (nt < 4) { dst = zb;  ld = DI;   nc0 = nt * 64; }
        else        { dst = xbc; ld = CDIM; nc0 = nt * 64 - 256; }
        #pragma unroll
        for (int mt = 0; mt < 2; mt++)
            #pragma unroll
            for (int ntt = 0; ntt < 2; ntt++) {
                int n = nc0 + wn * 32 + ntt * 16 + fr;
                #pragma unroll
                for (int rr = 0; rr < 4; rr++) {
                    int m = m0 + wm * 32 + mt * 16 + ko * 4 + rr;
                    dst[(size_t)m * ld + n] = f2bfbits(acc[mt][ntt][rr]);
                }
            }
    }
}

// ---------------- 3+5a. fused conv + SSD pass 1 --------------------------------
__global__ __launch_bounds__(512) void k_conv1(const unsigned short* __restrict__ xbc,
                                               const float* __restrict__ cw,
                                               const float* __restrict__ cb,
                                               const float* __restrict__ dtf,
                                               const float* __restrict__ alog,
                                               unsigned short* __restrict__ bcA,
                                               unsigned short* __restrict__ xT,
                                               unsigned short* __restrict__ hst,
                                               float* __restrict__ dAp) {
    __shared__ __align__(16) unsigned short L[320][72];
    __shared__ float wlh[NH][64];
    const int tid = threadIdx.x;
    const int t0 = blockIdx.x * 64;
    if (tid < CDIM) {
        const int ch = tid;
        const int l0 = t0 & (LSEQ - 1);
        float4 wv = *(const float4*)(cw + ch * 4);
        float bias = cb[ch];
        const unsigned short* in = xbc + (size_t)t0 * CDIM + ch;
        float h1 = 0.f, h2 = 0.f, h3 = 0.f;
        if (l0) {
            h1 = bfbits2f(in[-CDIM]);
            h2 = bfbits2f(in[-2 * CDIM]);
            h3 = bfbits2f(in[-3 * CDIM]);
        }
        short8 pk;
        #pragma unroll 8
        for (int t = 0; t < 64; t++) {
            float x0 = bfbits2f(in[(size_t)t * CDIM]);
            float acc = bias;
            acc = fmaf(x0, wv.w, acc);
            acc = fmaf(h1, wv.z, acc);
            acc = fmaf(h2, wv.y, acc);
            acc = fmaf(h3, wv.x, acc);
            float s = acc / (1.f + expf(-acc));
            unsigned short us = f2bfbits(s);
            if (ch >= 256) bcA[(size_t)(t0 + t) * 128 + (ch - 256)] = us;  // B|C tok-major
            pk[t & 7] = (short)us;
            if (ch < 320 && (t & 7) == 7) *(short8*)&L[ch][t - 7] = pk;
            h3 = h2; h2 = h1; h1 = x0;
        }
    }
    __syncthreads();
    {
        int idx = tid;
        #pragma unroll
        for (int it = 0; it < 4; it++, idx += 512) {
            int row = idx >> 3, tc = (idx & 7) * 8;
            *(short8*)(xT + (size_t)row * NTOK + t0 + tc) = *(const short8*)&L[row][tc];
        }
    }
    const int h = tid >> 6, lane = tid & 63;
    const int b = blockIdx.x >> 6, c = blockIdx.x & 63;
    const int bh = b * NH + h;
    const float A = -expf(alog[h]);
    float dt = dtf[(size_t)(t0 + lane) * NH + h];
    float q = dt * A * LOG2E;
    #pragma unroll
    for (int o = 1; o <= 32; o <<= 1) {
        float tmp = __shfl_up(q, o);
        if (lane >= o) q += tmp;
    }
    float qL = __shfl(q, 63);
    wlh[h][lane] = exp2f(qL - q) * dt;        // intra-wave LDS: no barrier needed
    if (lane == 0) dAp[(size_t)bh * NC + c] = exp2f(qL);
    const int m = lane & 15, ko = lane >> 4;
    f32x4 hacc[4][2] = {};
    #pragma unroll
    for (int kh = 0; kh < 2; kh++) {
        bf16x8 xb[2];
        #pragma unroll
        for (int pi = 0; pi < 2; pi++)
            xb[pi] = *(const bf16x8*)&L[h * HD + pi * 16 + m][kh * 32 + ko * 8];
        f32x4 w0 = *(const f32x4*)&wlh[h][kh * 32 + ko * 8];
        f32x4 w1v = *(const f32x4*)&wlh[h][kh * 32 + ko * 8 + 4];
        #pragma unroll
        for (int ni = 0; ni < 4; ni++) {
            bf16x8 bv = *(const bf16x8*)&L[256 + ni * 16 + m][kh * 32 + ko * 8];
            bf16x8 af;
            #pragma unroll
            for (int j = 0; j < 4; j++) af[j] = (bf16)((float)bv[j] * w0[j]);
            #pragma unroll
            for (int j = 0; j < 4; j++) af[4 + j] = (bf16)((float)bv[4 + j] * w1v[j]);
            #pragma unroll
            for (int pi = 0; pi < 2; pi++)
                hacc[ni][pi] = __builtin_amdgcn_mfma_f32_16x16x32_bf16(af, xb[pi], hacc[ni][pi], 0, 0, 0);
        }
    }
    unsigned short* hb = hst + (((size_t)bh * NC + c) << 11);
    #pragma unroll
    for (int ni = 0; ni < 4; ni++)
        #pragma unroll
        for (int pi = 0; pi < 2; pi++) {
            bf16x4 pv;
            #pragma unroll
            for (int r = 0; r < 4; r++) pv[r] = (bf16)hacc[ni][pi][r];
            *(bf16x4*)(hb + (pi * 16 + m) * 64 + ni * 16 + ko * 4) = pv;
        }
}

// ---------------- 5b. SSM pass 2: scan, 1 bh/block, depth-4 load pipeline ------
__global__ __launch_bounds__(256) void k_ssm2(unsigned short* __restrict__ hst,
                                              const float* __restrict__ dAp) {
    __shared__ float dl[NC];
    const int bh = blockIdx.x >> 3, seg = blockIdx.x & 7;
    const int s = seg * 256 + threadIdx.x;
    if (threadIdx.x < NC) dl[threadIdx.x] = dAp[(size_t)bh * NC + threadIdx.x];
    __syncthreads();
    unsigned short* p = hst + ((size_t)bh * NC << 11) + s;
    float r = 0.f;
    float v0 = bfbits2f(p[0]);
    float v1 = bfbits2f(p[(size_t)1 << 11]);
    float v2 = bfbits2f(p[(size_t)2 << 11]);
    float v3 = bfbits2f(p[(size_t)3 << 11]);
    for (int c = 0; c < NC; c += 4) {
        float t;
        t = v0; if (c + 4 < NC) v0 = bfbits2f(p[(size_t)(c + 4) << 11]);
        p[(size_t)c << 11] = f2bfbits(r);       r = fmaf(r, dl[c], t);
        t = v1; if (c + 5 < NC) v1 = bfbits2f(p[(size_t)(c + 5) << 11]);
        p[(size_t)(c + 1) << 11] = f2bfbits(r); r = fmaf(r, dl[c + 1], t);
        t = v2; if (c + 6 < NC) v2 = bfbits2f(p[(size_t)(c + 6) << 11]);
        p[(size_t)(c + 2) << 11] = f2bfbits(r); r = fmaf(r, dl[c + 2], t);
        t = v3; if (c + 7 < NC) v3 = bfbits2f(p[(size_t)(c + 7) << 11]);
        p[(size_t)(c + 3) << 11] = f2bfbits(r); r = fmaf(r, dl[c + 3], t);
    }
}

// ---------------- 5c+6+7. fused SSD pass 3 + gate + GEMM2 + residual -----------
// Block = one 64-token chunk, 8 waves = 8 heads. B/C staged once into LDS
// (shared by all heads). P built per s-half (64x32, wave-private, no barriers).
// After PV, the P buffer is re-used (aliased) as the 64x256 Y staging tile;
// epilogue: waves (rg, rg+4) split the 128 output cols of rows rg*16..+15.
__global__ __launch_bounds__(512, 2) void k_ssd3g(const unsigned short* __restrict__ bcA,
                                                  const unsigned short* __restrict__ xT,
                                                  const float* __restrict__ dtf,
                                                  const float* __restrict__ alog,
                                                  const unsigned short* __restrict__ hst,
                                                  const float* __restrict__ Dw,
                                                  const unsigned short* __restrict__ zb,
                                                  const unsigned short* __restrict__ w2f,
                                                  const float* __restrict__ xin,
                                                  float* __restrict__ out) {
    __shared__ __align__(16) unsigned short BC[64][136];   // B|C chunk, all heads
    __shared__ __align__(16) bf16 PlY[NH][64 * 40];        // per-wave P half; alias: Ys[64][264]
    __shared__ float ql[NH][64];
    __shared__ float dl[NH][64];
    const int tid = threadIdx.x;
    const int b = blockIdx.x >> 6, c = blockIdx.x & 63;
    const int t0 = blockIdx.x * 64;
    const size_t tok0 = (size_t)t0;
    // stage B|C chunk: 64 tok x 128 ch
    {
        int idx = tid;
        #pragma unroll
        for (int it = 0; it < 2; it++, idx += 512) {
            int tok = idx >> 4, c8 = (idx & 15) * 8;
            *(short8*)&BC[tok][c8] = *(const short8*)(bcA + (tok0 + tok) * 128 + c8);
        }
    }
    __syncthreads();
    const int h = tid >> 6, lane = tid & 63;
    const int bh = b * NH + h;
    const float A = -expf(alog[h]);
    const float Dh = Dw[h];
    float dt = dtf[(tok0 + lane) * NH + h];
    float q = dt * A * LOG2E;
    #pragma unroll
    for (int o = 1; o <= 32; o <<= 1) {
        float tmp = __shfl_up(q, o);
        if (lane >= o) q += tmp;
    }
    ql[h][lane] = q;                           // intra-wave LDS, no barrier
    dl[h][lane] = dt;
    const int m = lane & 15, ko = lane >> 4;
    bf16* Pw = &PlY[h][0];
    // C fragments (A-op for U, B-op for G^T)
    bf16x8 cf[4][2];
    #pragma unroll
    for (int ti = 0; ti < 4; ti++)
        #pragma unroll
        for (int kh = 0; kh < 2; kh++)
            cf[ti][kh] = *(const bf16x8*)&BC[ti * 16 + m][64 + kh * 32 + ko * 8];
    float qt[4];
    #pragma unroll
    for (int ti = 0; ti < 4; ti++) qt[ti] = ql[h][ti * 16 + m];
    // U = C . h_in^T
    const size_t hbase = ((size_t)bh * NC + c) << 11;
    f32x4 ya[4][2] = {}, ua[4][2] = {};
    #pragma unroll
    for (int kh = 0; kh < 2; kh++) {
        bf16x8 hb2[2];
        #pragma unroll
        for (int pi = 0; pi < 2; pi++)
            hb2[pi] = *(const bf16x8*)(hst + hbase + (pi * 16 + m) * 64 + kh * 32 + ko * 8);
        #pragma unroll
        for (int ti = 0; ti < 4; ti++)
            #pragma unroll
            for (int pi = 0; pi < 2; pi++)
                ua[ti][pi] = __builtin_amdgcn_mfma_f32_16x16x32_bf16(cf[ti][kh], hb2[pi], ua[ti][pi], 0, 0, 0);
    }
    // P half-tiles + PV
    #pragma unroll
    for (int sh = 0; sh < 2; sh++) {
        f32x4 gth[4][2] = {};
        #pragma unroll
        for (int kh = 0; kh < 2; kh++) {
            bf16x8 bfg[2];
            #pragma unroll
            for (int sj = 0; sj < 2; sj++)
                bfg[sj] = *(const bf16x8*)&BC[(sh * 2 + sj) * 16 + m][kh * 32 + ko * 8];
            #pragma unroll
            for (int ti = 0; ti < 4; ti++)
                #pragma unroll
                for (int sj = 0; sj < 2; sj++)
                    gth[ti][sj] = __builtin_amdgcn_mfma_f32_16x16x32_bf16(bfg[sj], cf[ti][kh], gth[ti][sj], 0, 0, 0);
        }
        #pragma unroll
        for (int sj = 0; sj < 2; sj++) {
            const int si = sh * 2 + sj;
            f32x4 qs = *(const f32x4*)&ql[h][si * 16 + ko * 4];
            f32x4 ds = *(const f32x4*)&dl[h][si * 16 + ko * 4];
            #pragma unroll
            for (int ti = 0; ti < 4; ti++) {
                bf16x4 pv = {};
                if (si <= ti) {
                    const int t = ti * 16 + m;
                    #pragma unroll
                    for (int r = 0; r < 4; r++) {
                        int s = si * 16 + ko * 4 + r;
                        float p = 0.f;
                        if (s <= t) {
                            p = exp2f(qt[ti] - qs[r]) * ds[r] * gth[ti][sj][r];
                            if (s == t) p += Dh;
                        }
                        pv[r] = (bf16)p;
                    }
                }
                *(bf16x4*)&Pw[(ti * 16 + m) * 40 + sj * 16 + ko * 4] = pv;
            }
        }
        bf16x8 xb[2];
        #pragma unroll
        for (int pi = 0; pi < 2; pi++)
            xb[pi] = *(const bf16x8*)(xT + (size_t)(h * HD + pi * 16 + m) * NTOK + tok0 + sh * 32 + ko * 8);
        #pragma unroll
        for (int ti = 0; ti < 4; ti++) {
            bf16x8 pa = *(const bf16x8*)&Pw[(ti * 16 + m) * 40 + ko * 8];
            #pragma unroll
            for (int pi = 0; pi < 2; pi++)
                ya[ti][pi] = __builtin_amdgcn_mfma_f32_16x16x32_bf16(pa, xb[pi], ya[ti][pi], 0, 0, 0);
        }
    }
    // y -> LDS staging (alias onto PlY; all waves must be done reading Pw)
    __syncthreads();
    unsigned short* Ys = (unsigned short*)&PlY[0][0];    // [64][264]
    {
        f32x4 et[4];
        #pragma unroll
        for (int ti = 0; ti < 4; ti++) {
            f32x4 qv = *(const f32x4*)&ql[h][ti * 16 + ko * 4];
            #pragma unroll
            for (int r = 0; r < 4; r++) et[ti][r] = exp2f(qv[r]);
        }
        #pragma unroll
        for (int ti = 0; ti < 4; ti++)
            #pragma unroll
            for (int pi = 0; pi < 2; pi++)
                #pragma unroll
                for (int r = 0; r < 4; r++) {
                    int t = ti * 16 + ko * 4 + r;
                    Ys[t * 264 + h * HD + pi * 16 + m] =
                        f2bfbits(ya[ti][pi][r] + et[ti][r] * ua[ti][pi][r]);
                }
    }
    __syncthreads();
    // epilogue: gate + RMSNorm + GEMM2 + residual
    {
        const int rg = h & 3, nh = h >> 2;
        const int r0 = rg * 16;
        const size_t rowo = (tok0 + r0 + m) * DI;
        float ss = 0.f;
        bf16x8 gb[8];
        #pragma unroll
        for (int kk = 0; kk < 8; kk++) {
            int co = kk * 32 + ko * 8;
            bf16x8 yv = *(const bf16x8*)&Ys[(r0 + m) * 264 + co];
            bf16x8 zv = *(const bf16x8*)(zb + rowo + co);
            #pragma unroll
            for (int j = 0; j < 8; j++) {
                float z = (float)zv[j];
                float g = (float)yv[j] * (z / (1.f + expf(-z)));
                ss += g * g;
                gb[kk][j] = (bf16)g;
            }
        }
        ss += __shfl_xor(ss, 16);
        ss += __shfl_xor(ss, 32);
        const float rs = rsqrtf(ss * (1.0f / DI) + EPSF);
        #pragma unroll
        for (int kk = 0; kk < 8; kk++)
            #pragma unroll
            for (int j = 0; j < 8; j++)
                gb[kk][j] = (bf16)((float)gb[kk][j] * rs);
        const unsigned short* wp = w2f + (size_t)lane * 8;
        f32x4 acc[4] = {};
        #pragma unroll
        for (int kk = 0; kk < 8; kk++) {
            #pragma unroll
            for (int ntl = 0; ntl < 4; ntl++) {
                bf16x8 bfr = *(const bf16x8*)(wp + (((size_t)kk * 8 + nh * 4 + ntl) << 9));
                acc[ntl] = __builtin_amdgcn_mfma_f32_16x16x32_bf16(gb[kk], bfr, acc[ntl], 0, 0, 0);
            }
        }
        #pragma unroll
        for (int ntl = 0; ntl < 4; ntl++) {
            int n = (nh * 4 + ntl) * 16 + m;
            #pragma unroll
            for (int rr = 0; rr < 4; rr++) {
                size_t row = tok0 + r0 + ko * 4 + rr;
                out[row * DM + n] = xin[row * DM + n] + acc[ntl][rr];
            }
        }
    }
}

extern "C" void kernel_launch(void* const* d_in, const int* in_sizes, int n_in,
                              void* d_out, int out_size, void* d_ws, size_t ws_size,
                              hipStream_t stream) {
    const float* x   = (const float*)d_in[0];
    const float* nw  = (const float*)d_in[1];
    const float* w1  = (const float*)d_in[2];
    const float* cw  = (const float*)d_in[3];
    const float* cb  = (const float*)d_in[4];
    const float* dtb = (const float*)d_in[5];
    const float* al  = (const float*)d_in[6];
    const float* Dw  = (const float*)d_in[7];
    const float* gw  = (const float*)d_in[8];
    const float* w2  = (const float*)d_in[9];
    float* out = (float*)d_out;

    float* ws = (float*)d_ws;
    float*  dAp = ws;                                   // 4096 fp32
    float*  dtf = dAp + NB * NH * NC;                   // NTOK*8 fp32
    unsigned short* hst = (unsigned short*)(dtf + (size_t)NTOK * NH); // 64*64*2048 bf16
    unsigned short* zb  = hst + (size_t)NB * NH * NC * 2048;          // NTOK*256
    unsigned short* xbc = zb + (size_t)NTOK * DI;                     // NTOK*384 (pre-conv)
    unsigned short* bcA = xbc + (size_t)NTOK * CDIM;                  // NTOK*128 (B|C tok-major)
    unsigned short* xT  = bcA + (size_t)NTOK * 128;                   // 256*NTOK (x ch-major)
    unsigned short* w1g = xT + (size_t)DI * NTOK;                     // 640*128 frag-packed
    unsigned short* w2f = w1g + (size_t)640 * DM;                     // 128*256 frag-packed

    k_prep<<<(640 * DM + DM * DI + 255) / 256, 256, 0, stream>>>(w1, w2, gw, w1g, w2f);
    k_gemm1<<<dim3(NTOK / 64, 2), 256, 0, stream>>>(x, nw, w1, dtb, w1g, zb, xbc, dtf);
    k_conv1<<<NTOK / 64, 512, 0, stream>>>(xbc, cw, cb, dtf, al, bcA, xT, hst, dAp);
    k_ssm2<<<NB * NH * 8, 256, 0, stream>>>(hst, dAp);
    k_ssd3g<<<NTOK / 64, 512, 0, stream>>>(bcA, xT, dtf, al, hst, Dw, zb, w2f, x, out);
}